// Round 1
// baseline (4609.083 us; speedup 1.0000x reference)
//
#include <hip/hip_runtime.h>

#define IN_DIM 32
#define HID 128
#define DEG 16

__device__ __forceinline__ float sigf(float x)   { return 1.0f / (1.0f + __expf(-x)); }
__device__ __forceinline__ float lreluf(float x) { return x > 0.0f ? x : 0.01f * x; }

// ---------------- init: state = x0, hidden = 0, out[0,:,0:32] = x0 ----------------
__global__ void init_kernel(const float* __restrict__ x0, float* __restrict__ state,
                            float* __restrict__ hidden, float* __restrict__ out, int N)
{
    int i = blockIdx.x * 256 + threadIdx.x;
    if (i < N * HID) hidden[i] = 0.0f;
    if (i < N * IN_DIM) {
        float v = x0[i];
        state[i] = v;
        int n = i >> 5, c = i & 31;
        out[(size_t)n * (2 * IN_DIM) + c] = v;
    }
}

// ---------------- attention projection vectors: va[j] = sum_c attn[c] * W[c,j] ----------------
__global__ void attnvec_kernel(const float* __restrict__ fc1, const float* __restrict__ attn1,
                               const float* __restrict__ fc2, const float* __restrict__ attn2,
                               float* __restrict__ va1, float* __restrict__ vd1,
                               float* __restrict__ va2, float* __restrict__ vd2)
{
    int j = threadIdx.x;  // 128 threads
    float a1 = 0, d1 = 0, a2 = 0, d2 = 0;
    for (int c = 0; c < 128; ++c) {
        float w = fc1[c * HID + j];
        a1 += attn1[c] * w;
        d1 += attn1[128 + c] * w;
    }
    for (int c = 0; c < 32; ++c) {
        float w = fc2[c * HID + j];
        a2 += attn2[c] * w;
        d2 += attn2[32 + c] * w;
    }
    va1[j] = a1; vd1[j] = d1; va2[j] = a2; vd2[j] = d2;
}

// ---------------- GRU: hout = GRU(state, hin); block = 256 nodes x 32 cols (grid.y = col group) ----------------
__global__ __launch_bounds__(256)
void gru_kernel(const float* __restrict__ state, const float* __restrict__ hin,
                float* __restrict__ hout,
                const float* __restrict__ Wih, const float* __restrict__ Whh,
                const float* __restrict__ bih, const float* __restrict__ bhh, int N)
{
    __shared__ float lWih[3][32][IN_DIM];   // 12 KB
    __shared__ float lWhh[3][32][HID];      // 48 KB
    __shared__ float lbr[32], lbz[32], lbni[32], lbnh[32];

    const int tid = threadIdx.x;
    const int cg  = blockIdx.y;             // 0..3 column group (32 cols each)
    const int n   = blockIdx.x * 256 + tid;

    for (int idx = tid; idx < 3 * 32 * IN_DIM; idx += 256) {
        int g = idx / (32 * IN_DIM), r = (idx / IN_DIM) & 31, k = idx & (IN_DIM - 1);
        lWih[g][r][k] = Wih[(size_t)(g * HID + cg * 32 + r) * IN_DIM + k];
    }
    for (int idx = tid; idx < 3 * 32 * HID; idx += 256) {
        int g = idx / (32 * HID), r = (idx / HID) & 31, k = idx & (HID - 1);
        lWhh[g][r][k] = Whh[(size_t)(g * HID + cg * 32 + r) * HID + k];
    }
    if (tid < 32) {
        int j = cg * 32 + tid;
        lbr[tid]  = bih[j] + bhh[j];
        lbz[tid]  = bih[HID + j] + bhh[HID + j];
        lbni[tid] = bih[2 * HID + j];
        lbnh[tid] = bhh[2 * HID + j];
    }
    __syncthreads();
    if (n >= N) return;  // no further syncs below

    float x[IN_DIM], h[HID];
    {
        const float4* xp = (const float4*)(state + (size_t)n * IN_DIM);
        #pragma unroll
        for (int q = 0; q < IN_DIM / 4; ++q) {
            float4 v = xp[q];
            x[4*q+0] = v.x; x[4*q+1] = v.y; x[4*q+2] = v.z; x[4*q+3] = v.w;
        }
        const float4* hp = (const float4*)(hin + (size_t)n * HID);
        #pragma unroll
        for (int q = 0; q < HID / 4; ++q) {
            float4 v = hp[q];
            h[4*q+0] = v.x; h[4*q+1] = v.y; h[4*q+2] = v.z; h[4*q+3] = v.w;
        }
    }
    const float* hrow = hin  + (size_t)n * HID + cg * 32;
    float*       orow = hout + (size_t)n * HID + cg * 32;

    #pragma unroll 1
    for (int jj = 0; jj < 32; ++jj) {
        float rs = lbr[jj], zs = lbz[jj], nis = lbni[jj], nhs = lbnh[jj];
        #pragma unroll
        for (int k = 0; k < IN_DIM; ++k) {
            float xv = x[k];
            rs  = fmaf(lWih[0][jj][k], xv, rs);
            zs  = fmaf(lWih[1][jj][k], xv, zs);
            nis = fmaf(lWih[2][jj][k], xv, nis);
        }
        #pragma unroll
        for (int k = 0; k < HID; ++k) {
            float hv = h[k];
            rs  = fmaf(lWhh[0][jj][k], hv, rs);
            zs  = fmaf(lWhh[1][jj][k], hv, zs);
            nhs = fmaf(lWhh[2][jj][k], hv, nhs);
        }
        float r  = sigf(rs);
        float zg = sigf(zs);
        float nc = tanhf(fmaf(r, nhs, nis));
        float hold = hrow[jj];
        orow[jj] = (1.0f - zg) * nc + zg * hold;
    }
}

// ---------------- z = in @ W^T (+ per-node attention dots ps,pd on wave 0) ----------------
// block = 64 nodes (lane) x 4 waves; each wave computes MC cols; grid.y shifts by 4*MC cols
template<int MTOT, int MC>
__global__ __launch_bounds__(256)
void z_kernel(const float* __restrict__ in, const float* __restrict__ W,
              const float* __restrict__ va, const float* __restrict__ vd,
              float* __restrict__ z, float* __restrict__ ps, float* __restrict__ pd, int N)
{
    constexpr int CB = 4 * MC;
    __shared__ float lW[CB][HID];

    const int tid = threadIdx.x;
    const int w = tid >> 6, lane = tid & 63;
    const int colbase = blockIdx.y * CB;
    const int n = blockIdx.x * 64 + lane;

    for (int idx = tid; idx < CB * HID; idx += 256) {
        int r = idx >> 7, k = idx & 127;
        lW[r][k] = W[(size_t)(colbase + r) * HID + k];
    }
    __syncthreads();
    if (n >= N) return;

    float h[HID];
    const float4* hp = (const float4*)(in + (size_t)n * HID);
    #pragma unroll
    for (int q = 0; q < HID / 4; ++q) {
        float4 v = hp[q];
        h[4*q+0] = v.x; h[4*q+1] = v.y; h[4*q+2] = v.z; h[4*q+3] = v.w;
    }

    float* zrow = z + (size_t)n * MTOT + colbase + w * MC;
    #pragma unroll 1
    for (int jj = 0; jj < MC; ++jj) {
        float acc = 0.0f;
        #pragma unroll
        for (int k = 0; k < HID; ++k) acc = fmaf(lW[w * MC + jj][k], h[k], acc);
        zrow[jj] = acc;
    }

    if (w == 0 && blockIdx.y == 0) {
        float pa = 0.0f, pb = 0.0f;
        #pragma unroll
        for (int k = 0; k < HID; ++k) {
            pa = fmaf(h[k], va[k], pa);
            pb = fmaf(h[k], vd[k], pb);
        }
        ps[n] = pa;
        pd[n] = pb;
    }
}

// ---------------- GAT layer 1 aggregate (D = 128), wave per node, relu fused ----------------
__global__ __launch_bounds__(256)
void gat1_kernel(const float* __restrict__ z, const float* __restrict__ ps, const float* __restrict__ pd,
                 const int* __restrict__ src, float* __restrict__ g1, int N)
{
    const int lane = threadIdx.x & 63;
    const int i = blockIdx.x * 4 + (threadIdx.x >> 6);
    if (i >= N) return;

    int s = 0; float e = -3.0e38f;
    if (lane < DEG) {
        s = src[i * DEG + lane];
        e = lreluf(ps[s] + pd[i]);
    }
    float m = e;
    m = fmaxf(m, __shfl_xor(m, 8));
    m = fmaxf(m, __shfl_xor(m, 4));
    m = fmaxf(m, __shfl_xor(m, 2));
    m = fmaxf(m, __shfl_xor(m, 1));
    float ee = (lane < DEG) ? __expf(e - m) : 0.0f;
    float sum = ee;
    sum += __shfl_xor(sum, 8);
    sum += __shfl_xor(sum, 4);
    sum += __shfl_xor(sum, 2);
    sum += __shfl_xor(sum, 1);
    float alpha = ee / sum;

    float a0 = 0.0f, a1 = 0.0f;
    #pragma unroll
    for (int k = 0; k < DEG; ++k) {
        float ak = __shfl(alpha, k);
        int   sk = __shfl(s, k);
        const float* row = z + (size_t)sk * HID;
        a0 = fmaf(ak, row[lane], a0);
        a1 = fmaf(ak, row[64 + lane], a1);
    }
    g1[(size_t)i * HID + lane]      = fmaxf(a0, 0.0f);
    g1[(size_t)i * HID + 64 + lane] = fmaxf(a1, 0.0f);
}

// ---------------- GAT layer 2 aggregate (D = 32) + state update + output writes ----------------
__global__ __launch_bounds__(256)
void gat2_kernel(const float* __restrict__ z, const float* __restrict__ ps, const float* __restrict__ pd,
                 const int* __restrict__ src, float* __restrict__ state,
                 float* __restrict__ out, const float* __restrict__ tarr,
                 int tstep, int N, int T)
{
    const int lane = threadIdx.x & 63;
    const int i = blockIdx.x * 4 + (threadIdx.x >> 6);
    if (i >= N) return;

    int s = 0; float e = -3.0e38f;
    if (lane < DEG) {
        s = src[i * DEG + lane];
        e = lreluf(ps[s] + pd[i]);
    }
    float m = e;
    m = fmaxf(m, __shfl_xor(m, 8));
    m = fmaxf(m, __shfl_xor(m, 4));
    m = fmaxf(m, __shfl_xor(m, 2));
    m = fmaxf(m, __shfl_xor(m, 1));
    float ee = (lane < DEG) ? __expf(e - m) : 0.0f;
    float sum = ee;
    sum += __shfl_xor(sum, 8);
    sum += __shfl_xor(sum, 4);
    sum += __shfl_xor(sum, 2);
    sum += __shfl_xor(sum, 1);
    float alpha = ee / sum;

    const int cl = lane & (IN_DIM - 1);
    float acc = 0.0f;
    #pragma unroll
    for (int k = 0; k < DEG; ++k) {
        float ak = __shfl(alpha, k);
        int   sk = __shfl(s, k);
        acc = fmaf(ak, z[(size_t)sk * IN_DIM + cl], acc);
    }

    float dt = (tstep < T - 1) ? (tarr[tstep + 1] - tarr[tstep]) : 0.0f;
    if (lane < IN_DIM) {
        size_t obase = ((size_t)tstep * N + i) * (2 * IN_DIM);
        out[obase + IN_DIM + lane] = acc;                 // xii slab
        if (tstep < T - 1) {
            float sv = state[(size_t)i * IN_DIM + lane];
            float sn = fmaf(dt, acc, sv);
            state[(size_t)i * IN_DIM + lane] = sn;
            out[obase + (size_t)N * (2 * IN_DIM) + lane] = sn;  // out[t+1,:,0:32]
        }
    }
}

extern "C" void kernel_launch(void* const* d_in, const int* in_sizes, int n_in,
                              void* d_out, int out_size, void* d_ws, size_t ws_size,
                              hipStream_t stream)
{
    const float* tarr  = (const float*)d_in[0];
    const float* x0    = (const float*)d_in[1];
    const int*   src   = (const int*)d_in[2];
    // d_in[3] = dst, structurally repeat(arange(N), DEG) — not needed
    const float* Wih   = (const float*)d_in[4];
    const float* Whh   = (const float*)d_in[5];
    const float* bih   = (const float*)d_in[6];
    const float* bhh   = (const float*)d_in[7];
    const float* fc1   = (const float*)d_in[8];
    const float* attn1 = (const float*)d_in[9];
    const float* fc2   = (const float*)d_in[10];
    const float* attn2 = (const float*)d_in[11];
    float* out = (float*)d_out;

    const int T = in_sizes[0];
    const int N = in_sizes[1] / IN_DIM;

    float* p = (float*)d_ws;
    float* state = p; p += (size_t)N * IN_DIM;
    float* hidA  = p; p += (size_t)N * HID;
    float* hidB  = p; p += (size_t)N * HID;
    float* z1    = p; p += (size_t)N * HID;
    float* g1b   = p; p += (size_t)N * HID;
    float* z2    = p; p += (size_t)N * IN_DIM;
    float* ps1   = p; p += N;
    float* pd1   = p; p += N;
    float* ps2   = p; p += N;
    float* pd2   = p; p += N;
    float* va1   = p; p += HID;
    float* vd1   = p; p += HID;
    float* va2   = p; p += HID;
    float* vd2   = p; p += HID;

    init_kernel<<<(N * HID + 255) / 256, 256, 0, stream>>>(x0, state, hidA, out, N);
    attnvec_kernel<<<1, 128, 0, stream>>>(fc1, attn1, fc2, attn2, va1, vd1, va2, vd2);

    for (int t = 0; t < T; ++t) {
        const float* hin = (t & 1) ? hidB : hidA;
        float*       hout = (t & 1) ? hidA : hidB;

        gru_kernel<<<dim3((N + 255) / 256, 4), 256, 0, stream>>>(
            state, hin, hout, Wih, Whh, bih, bhh, N);

        z_kernel<HID, 16><<<dim3((N + 63) / 64, 2), 256, 0, stream>>>(
            hout, fc1, va1, vd1, z1, ps1, pd1, N);

        gat1_kernel<<<(N + 3) / 4, 256, 0, stream>>>(z1, ps1, pd1, src, g1b, N);

        z_kernel<IN_DIM, 8><<<dim3((N + 63) / 64, 1), 256, 0, stream>>>(
            g1b, fc2, va2, vd2, z2, ps2, pd2, N);

        gat2_kernel<<<(N + 3) / 4, 256, 0, stream>>>(
            z2, ps2, pd2, src, state, out, tarr, t, N, T);
    }
}

// Round 2
// 1206.594 us; speedup vs baseline: 3.8199x; 3.8199x over previous
//
#include <hip/hip_runtime.h>

#define IN_DIM 32
#define HID 128
#define DEG 16
#define BM 64
#define APAD 168   // A-tile row stride (ushorts): 160 + 8, keeps 16B alignment + bank spread
#define HPAD 136   // h-tile row stride (ushorts): 128 + 8

typedef short bf16x8 __attribute__((ext_vector_type(8)));
typedef float f32x4 __attribute__((ext_vector_type(4)));

__device__ __forceinline__ float sigf(float x)   { return 1.0f / (1.0f + __expf(-x)); }
__device__ __forceinline__ float tanhfast(float x) {
    x = fminf(fmaxf(x, -15.0f), 15.0f);
    float e2 = __expf(2.0f * x);
    return (e2 - 1.0f) / (e2 + 1.0f);
}
__device__ __forceinline__ float lreluf(float x) { return x > 0.0f ? x : 0.01f * x; }
__device__ __forceinline__ unsigned short f2bf(float f) {
    unsigned int u = __float_as_uint(f);
    unsigned int r = (u + 0x7fffu + ((u >> 16) & 1u)) >> 16;
    return (unsigned short)r;
}
__device__ __forceinline__ float bf2f(unsigned short h) {
    return __uint_as_float(((unsigned int)h) << 16);
}
__device__ __forceinline__ f32x4 mfma16(bf16x8 a, bf16x8 b, f32x4 c) {
    return __builtin_amdgcn_mfma_f32_16x16x32_bf16(a, b, c, 0, 0, 0);
}

// ---------------- init ----------------
__global__ void init_kernel(const float* __restrict__ x0, float* __restrict__ state,
                            unsigned short* __restrict__ state_bf, unsigned short* __restrict__ hA,
                            float* __restrict__ out, int N)
{
    int i = blockIdx.x * 256 + threadIdx.x;
    if (i < N * HID) hA[i] = 0;
    if (i < N * IN_DIM) {
        float v = x0[i];
        state[i] = v;
        state_bf[i] = f2bf(v);
        int n = i >> 5, c = i & 31;
        out[(size_t)n * (2 * IN_DIM) + c] = v;
    }
}

// ---------------- attention projection vectors ----------------
__global__ void attnvec_kernel(const float* __restrict__ fc1, const float* __restrict__ attn1,
                               const float* __restrict__ fc2, const float* __restrict__ attn2,
                               float* __restrict__ va1, float* __restrict__ vd1,
                               float* __restrict__ va2, float* __restrict__ vd2)
{
    int j = threadIdx.x;  // 128
    float a1 = 0, d1 = 0, a2 = 0, d2 = 0;
    for (int c = 0; c < 128; ++c) {
        float w = fc1[c * HID + j];
        a1 += attn1[c] * w;
        d1 += attn1[128 + c] * w;
    }
    for (int c = 0; c < 32; ++c) {
        float w = fc2[c * HID + j];
        a2 += attn2[c] * w;
        d2 += attn2[32 + c] * w;
    }
    va1[j] = a1; vd1[j] = d1; va2[j] = a2; vd2[j] = d2;
}

// ---------------- bias combine ----------------
__global__ void bias_kernel(const float* __restrict__ bih, const float* __restrict__ bhh,
                            float* __restrict__ br, float* __restrict__ bz,
                            float* __restrict__ bni, float* __restrict__ bnh)
{
    int j = threadIdx.x;  // 128
    br[j]  = bih[j] + bhh[j];
    bz[j]  = bih[HID + j] + bhh[HID + j];
    bni[j] = bih[2 * HID + j];
    bnh[j] = bhh[2 * HID + j];
}

// ---------------- weight packers into B-fragment order ----------------
// pack[((kc*NCT+ct)*64 + lane)*8 + j] = W_ext[c = ct*16 + (lane&15)][k = kc*32 + ((lane>>4))*8 + j]
__global__ void pack_gru_kernel(const float* __restrict__ Wih, const float* __restrict__ Whh,
                                unsigned short* __restrict__ pk)   // 512 cols x 160 K, NCT=32, KC=5
{
    int idx = blockIdx.x * 256 + threadIdx.x;
    if (idx >= 5 * 32 * 64 * 8) return;
    int j = idx & 7, lane = (idx >> 3) & 63, tile = idx >> 9;
    int ct = tile & 31, kc = tile >> 5;
    int c = ct * 16 + (lane & 15);
    int k = kc * 32 + (lane >> 4) * 8 + j;
    float v;
    if (c < 256)      v = (k < 32) ? Wih[(size_t)c * 32 + k] : Whh[(size_t)c * 128 + (k - 32)];
    else if (c < 384) v = (k < 32) ? Wih[(size_t)c * 32 + k] : 0.0f;
    else              v = (k < 32) ? 0.0f : Whh[(size_t)(c - 128) * 128 + (k - 32)];
    pk[idx] = f2bf(v);
}

__global__ void pack_fc1_kernel(const float* __restrict__ fc1, const float* __restrict__ va1,
                                const float* __restrict__ vd1, unsigned short* __restrict__ pk)
{   // 144 cols x 128 K, NCT=9, KC=4
    int idx = blockIdx.x * 256 + threadIdx.x;
    if (idx >= 4 * 9 * 64 * 8) return;
    int j = idx & 7, lane = (idx >> 3) & 63, tile = idx >> 9;
    int ct = tile % 9, kc = tile / 9;
    int c = ct * 16 + (lane & 15);
    int k = kc * 32 + (lane >> 4) * 8 + j;
    float v;
    if (c < 128)      v = fc1[(size_t)c * 128 + k];
    else if (c == 128) v = va1[k];
    else if (c == 129) v = vd1[k];
    else               v = 0.0f;
    pk[idx] = f2bf(v);
}

__global__ void pack_fc2_kernel(const float* __restrict__ fc2, const float* __restrict__ va2,
                                const float* __restrict__ vd2, unsigned short* __restrict__ pk)
{   // 48 cols x 128 K, NCT=3, KC=4
    int idx = blockIdx.x * 256 + threadIdx.x;
    if (idx >= 4 * 3 * 64 * 8) return;
    int j = idx & 7, lane = (idx >> 3) & 63, tile = idx >> 9;
    int ct = tile % 3, kc = tile / 3;
    int c = ct * 16 + (lane & 15);
    int k = kc * 32 + (lane >> 4) * 8 + j;
    float v;
    if (c < 32)       v = fc2[(size_t)c * 128 + k];
    else if (c == 32) v = va2[k];
    else if (c == 33) v = vd2[k];
    else              v = 0.0f;
    pk[idx] = f2bf(v);
}

// ---------------- K1: GRU (MFMA) + z1ext GEMM fused ----------------
__global__ __launch_bounds__(256)
void k1_gru_z1(const unsigned short* __restrict__ xbf,    // state bf16 [N][32]
               const unsigned short* __restrict__ hin,    // h bf16 [N][128]
               unsigned short* __restrict__ hout,         // h bf16 [N][128]
               const unsigned short* __restrict__ Wg,     // packed 512x160
               const unsigned short* __restrict__ Fc1,    // packed 144x128
               const float* __restrict__ br, const float* __restrict__ bz,
               const float* __restrict__ bni, const float* __restrict__ bnh,
               unsigned short* __restrict__ z1,           // bf16 [N][128]
               float* __restrict__ ps1, float* __restrict__ pd1, int N)
{
    __shared__ unsigned short A[BM][APAD];   // [x | h_old], 21.5 KB
    __shared__ unsigned short Ht[BM][HPAD];  // h_new, 17.4 KB

    const int tid = threadIdx.x;
    const int lane = tid & 63, w = tid >> 6;
    const int n0 = blockIdx.x * BM;
    const int row = lane & 15, kg = lane >> 4;

    // stage A = [x (32) | h_old (128)] rows, zero-fill tail
    for (int idx = tid; idx < BM * 20; idx += 256) {
        int r = idx / 20, seg = idx % 20;
        int n = n0 + r;
        bf16x8 v = {0, 0, 0, 0, 0, 0, 0, 0};
        if (n < N) {
            const unsigned short* src = (seg < 4) ? (xbf + (size_t)n * IN_DIM + seg * 8)
                                                  : (hin + (size_t)n * HID + (seg - 4) * 8);
            v = *(const bf16x8*)src;
        }
        *(bf16x8*)&A[r][seg * 8] = v;
    }
    __syncthreads();

    const int mt = w;  // wave = M-tile (16 rows)
    // ---- GEMM1: gates[64 x 512] ----
    for (int ctq = 0; ctq < 8; ++ctq) {
        f32x4 acc0 = {0, 0, 0, 0}, acc1 = {0, 0, 0, 0}, acc2 = {0, 0, 0, 0}, acc3 = {0, 0, 0, 0};
        #pragma unroll
        for (int kc = 0; kc < 5; ++kc) {
            bf16x8 a = *(const bf16x8*)&A[mt * 16 + row][kc * 32 + kg * 8];
            const size_t base = ((size_t)(kc * 32) * 64 + lane) * 8;
            bf16x8 b0 = *(const bf16x8*)(Wg + base + (size_t)(ctq)      * 64 * 8);
            bf16x8 b1 = *(const bf16x8*)(Wg + base + (size_t)(ctq + 8)  * 64 * 8);
            bf16x8 b2 = *(const bf16x8*)(Wg + base + (size_t)(ctq + 16) * 64 * 8);
            bf16x8 b3 = *(const bf16x8*)(Wg + base + (size_t)(ctq + 24) * 64 * 8);
            acc0 = mfma16(a, b0, acc0);
            acc1 = mfma16(a, b1, acc1);
            acc2 = mfma16(a, b2, acc2);
            acc3 = mfma16(a, b3, acc3);
        }
        // gate combine for cols ctq*16+row
        int col = ctq * 16 + row;
        float brv = br[col], bzv = bz[col], bniv = bni[col], bnhv = bnh[col];
        #pragma unroll
        for (int rr = 0; rr < 4; ++rr) {
            int r_loc = mt * 16 + kg * 4 + rr;
            float rg = sigf(acc0[rr] + brv);
            float zg = sigf(acc1[rr] + bzv);
            float nc = tanhfast(acc2[rr] + bniv + rg * (acc3[rr] + bnhv));
            float hold = bf2f(A[r_loc][32 + col]);
            float hn = (1.0f - zg) * nc + zg * hold;
            unsigned short hb = f2bf(hn);
            Ht[r_loc][col] = hb;
            int n = n0 + r_loc;
            if (n < N) hout[(size_t)n * HID + col] = hb;
        }
    }
    __syncthreads();

    // ---- GEMM2: z1ext[64 x 144] = h_new @ fc1ext^T ----
    for (int ct = 0; ct < 9; ++ct) {
        f32x4 acc = {0, 0, 0, 0};
        #pragma unroll
        for (int kc = 0; kc < 4; ++kc) {
            bf16x8 a = *(const bf16x8*)&Ht[mt * 16 + row][kc * 32 + kg * 8];
            bf16x8 b = *(const bf16x8*)(Fc1 + ((size_t)(kc * 9 + ct) * 64 + lane) * 8);
            acc = mfma16(a, b, acc);
        }
        int col = ct * 16 + row;
        #pragma unroll
        for (int rr = 0; rr < 4; ++rr) {
            int n = n0 + mt * 16 + kg * 4 + rr;
            if (n < N) {
                if (col < 128)       z1[(size_t)n * HID + col] = f2bf(acc[rr]);
                else if (col == 128) ps1[n] = acc[rr];
                else if (col == 129) pd1[n] = acc[rr];
            }
        }
    }
}

// ---------------- K2: GAT1 aggregate + z2ext GEMM fused ----------------
__global__ __launch_bounds__(256)
void k2_gat1_z2(const unsigned short* __restrict__ z1, const float* __restrict__ ps1,
                const float* __restrict__ pd1, const int* __restrict__ src,
                const unsigned short* __restrict__ Fc2,
                unsigned short* __restrict__ z2, float* __restrict__ ps2,
                float* __restrict__ pd2, int N)
{
    __shared__ unsigned short G[BM][HPAD];

    const int tid = threadIdx.x;
    const int lane = tid & 63, w = tid >> 6;
    const int n0 = blockIdx.x * BM;
    const int row = lane & 15, kg = lane >> 4;

    // phase 1: per-wave, 16 nodes each: softmax over 16 in-edges + aggregate 128 cols
    for (int it = 0; it < 16; ++it) {
        int iloc = w * 16 + it;
        int i = n0 + iloc;
        int s = 0; float e = -3.0e38f;
        bool valid = (i < N);
        if (valid && lane < DEG) {
            s = src[i * DEG + lane];
            e = lreluf(ps1[s] + pd1[i]);
        }
        float m = e;
        m = fmaxf(m, __shfl_xor(m, 8));
        m = fmaxf(m, __shfl_xor(m, 4));
        m = fmaxf(m, __shfl_xor(m, 2));
        m = fmaxf(m, __shfl_xor(m, 1));
        float ee = (lane < DEG) ? __expf(e - m) : 0.0f;
        float sum = ee;
        sum += __shfl_xor(sum, 8);
        sum += __shfl_xor(sum, 4);
        sum += __shfl_xor(sum, 2);
        sum += __shfl_xor(sum, 1);
        float alpha = ee / sum;

        int sks[DEG];
        float als[DEG];
        #pragma unroll
        for (int k = 0; k < DEG; ++k) {
            sks[k] = __shfl(s, k);
            als[k] = __shfl(alpha, k);
        }
        float a0 = 0.0f, a1 = 0.0f;
        const int c2 = lane * 2;
        if (valid) {
            unsigned int vv[DEG];
            #pragma unroll
            for (int k = 0; k < DEG; ++k)
                vv[k] = *(const unsigned int*)(z1 + (size_t)sks[k] * HID + c2);
            #pragma unroll
            for (int k = 0; k < DEG; ++k) {
                a0 = fmaf(als[k], __uint_as_float((vv[k] & 0xffffu) << 16), a0);
                a1 = fmaf(als[k], __uint_as_float(vv[k] & 0xffff0000u), a1);
            }
        }
        G[iloc][c2]     = f2bf(fmaxf(a0, 0.0f));
        G[iloc][c2 + 1] = f2bf(fmaxf(a1, 0.0f));
    }
    __syncthreads();

    // phase 2: z2ext[64 x 48] = g1 @ fc2ext^T
    const int mt = w;
    for (int ct = 0; ct < 3; ++ct) {
        f32x4 acc = {0, 0, 0, 0};
        #pragma unroll
        for (int kc = 0; kc < 4; ++kc) {
            bf16x8 a = *(const bf16x8*)&G[mt * 16 + row][kc * 32 + kg * 8];
            bf16x8 b = *(const bf16x8*)(Fc2 + ((size_t)(kc * 3 + ct) * 64 + lane) * 8);
            acc = mfma16(a, b, acc);
        }
        int col = ct * 16 + row;
        #pragma unroll
        for (int rr = 0; rr < 4; ++rr) {
            int n = n0 + mt * 16 + kg * 4 + rr;
            if (n < N) {
                if (col < 32)        z2[(size_t)n * IN_DIM + col] = f2bf(acc[rr]);
                else if (col == 32)  ps2[n] = acc[rr];
                else if (col == 33)  pd2[n] = acc[rr];
            }
        }
    }
}

// ---------------- K3: GAT2 aggregate + state update + outputs ----------------
__global__ __launch_bounds__(256)
void k3_gat2(const unsigned short* __restrict__ z2, const float* __restrict__ ps2,
             const float* __restrict__ pd2, const int* __restrict__ src,
             float* __restrict__ state, unsigned short* __restrict__ state_bf,
             float* __restrict__ out, const float* __restrict__ tarr,
             int tstep, int N, int T)
{
    const int lane = threadIdx.x & 63;
    const int i = blockIdx.x * 4 + (threadIdx.x >> 6);
    if (i >= N) return;

    int s = 0; float e = -3.0e38f;
    if (lane < DEG) {
        s = src[i * DEG + lane];
        e = lreluf(ps2[s] + pd2[i]);
    }
    float m = e;
    m = fmaxf(m, __shfl_xor(m, 8));
    m = fmaxf(m, __shfl_xor(m, 4));
    m = fmaxf(m, __shfl_xor(m, 2));
    m = fmaxf(m, __shfl_xor(m, 1));
    float ee = (lane < DEG) ? __expf(e - m) : 0.0f;
    float sum = ee;
    sum += __shfl_xor(sum, 8);
    sum += __shfl_xor(sum, 4);
    sum += __shfl_xor(sum, 2);
    sum += __shfl_xor(sum, 1);
    float alpha = ee / sum;

    const int cl = lane & (IN_DIM - 1);
    float acc = 0.0f;
    #pragma unroll
    for (int k = 0; k < DEG; ++k) {
        float ak = __shfl(alpha, k);
        int   sk = __shfl(s, k);
        acc = fmaf(ak, bf2f(z2[(size_t)sk * IN_DIM + cl]), acc);
    }

    float dt = (tstep < T - 1) ? (tarr[tstep + 1] - tarr[tstep]) : 0.0f;
    if (lane < IN_DIM) {
        size_t obase = ((size_t)tstep * N + i) * (2 * IN_DIM);
        out[obase + IN_DIM + lane] = acc;                    // xii slab
        if (tstep < T - 1) {
            float sv = state[(size_t)i * IN_DIM + lane];
            float sn = fmaf(dt, acc, sv);
            state[(size_t)i * IN_DIM + lane] = sn;
            state_bf[(size_t)i * IN_DIM + lane] = f2bf(sn);
            out[obase + (size_t)N * (2 * IN_DIM) + lane] = sn;  // out[t+1,:,0:32]
        }
    }
}

extern "C" void kernel_launch(void* const* d_in, const int* in_sizes, int n_in,
                              void* d_out, int out_size, void* d_ws, size_t ws_size,
                              hipStream_t stream)
{
    const float* tarr  = (const float*)d_in[0];
    const float* x0    = (const float*)d_in[1];
    const int*   src   = (const int*)d_in[2];
    // d_in[3] = dst (structural: repeat(arange(N), DEG))
    const float* Wih   = (const float*)d_in[4];
    const float* Whh   = (const float*)d_in[5];
    const float* bih   = (const float*)d_in[6];
    const float* bhh   = (const float*)d_in[7];
    const float* fc1   = (const float*)d_in[8];
    const float* attn1 = (const float*)d_in[9];
    const float* fc2   = (const float*)d_in[10];
    const float* attn2 = (const float*)d_in[11];
    float* out = (float*)d_out;

    const int T = in_sizes[0];
    const int N = in_sizes[1] / IN_DIM;

    // f32 region
    float* fp = (float*)d_ws;
    float* state = fp; fp += (size_t)N * IN_DIM;
    float* ps1 = fp; fp += N;
    float* pd1 = fp; fp += N;
    float* ps2 = fp; fp += N;
    float* pd2 = fp; fp += N;
    float* va1 = fp; fp += HID;
    float* vd1 = fp; fp += HID;
    float* va2 = fp; fp += HID;
    float* vd2 = fp; fp += HID;
    float* br  = fp; fp += HID;
    float* bz  = fp; fp += HID;
    float* bni = fp; fp += HID;
    float* bnh = fp; fp += HID;
    // bf16 region
    unsigned short* up = (unsigned short*)fp;
    unsigned short* state_bf = up; up += (size_t)N * IN_DIM;
    unsigned short* hA  = up; up += (size_t)N * HID;
    unsigned short* hB  = up; up += (size_t)N * HID;
    unsigned short* z1  = up; up += (size_t)N * HID;
    unsigned short* z2  = up; up += (size_t)N * IN_DIM;
    unsigned short* Wg  = up; up += 5 * 32 * 64 * 8;
    unsigned short* F1p = up; up += 4 * 9 * 64 * 8;
    unsigned short* F2p = up; up += 4 * 3 * 64 * 8;

    const int nblk = (N + BM - 1) / BM;

    init_kernel<<<(N * HID + 255) / 256, 256, 0, stream>>>(x0, state, state_bf, hA, out, N);
    attnvec_kernel<<<1, 128, 0, stream>>>(fc1, attn1, fc2, attn2, va1, vd1, va2, vd2);
    bias_kernel<<<1, 128, 0, stream>>>(bih, bhh, br, bz, bni, bnh);
    pack_gru_kernel<<<(5 * 32 * 64 * 8 + 255) / 256, 256, 0, stream>>>(Wih, Whh, Wg);
    pack_fc1_kernel<<<(4 * 9 * 64 * 8 + 255) / 256, 256, 0, stream>>>(fc1, va1, vd1, F1p);
    pack_fc2_kernel<<<(4 * 3 * 64 * 8 + 255) / 256, 256, 0, stream>>>(fc2, va2, vd2, F2p);

    for (int t = 0; t < T; ++t) {
        const unsigned short* hin = (t & 1) ? hB : hA;
        unsigned short*      houtp = (t & 1) ? hA : hB;

        k1_gru_z1<<<nblk, 256, 0, stream>>>(state_bf, hin, houtp, Wg, F1p,
                                            br, bz, bni, bnh, z1, ps1, pd1, N);
        k2_gat1_z2<<<nblk, 256, 0, stream>>>(z1, ps1, pd1, src, F2p, z2, ps2, pd2, N);
        k3_gat2<<<(N + 3) / 4, 256, 0, stream>>>(z2, ps2, pd2, src, state, state_bf,
                                                 out, tarr, t, N, T);
    }
}

// Round 3
// 1158.269 us; speedup vs baseline: 3.9793x; 1.0417x over previous
//
#include <hip/hip_runtime.h>

#define IN_DIM 32
#define HID 128
#define DEG 16
#define BM 32
#define APAD 168   // A-tile row stride (ushorts)
#define HPAD 136   // h-tile row stride
#define ZPAD 40    // z2-stage row stride

typedef short bf16x8 __attribute__((ext_vector_type(8)));
typedef float f32x4 __attribute__((ext_vector_type(4)));

__device__ __forceinline__ float sigf(float x)   { return 1.0f / (1.0f + __expf(-x)); }
__device__ __forceinline__ float tanhfast(float x) {
    x = fminf(fmaxf(x, -15.0f), 15.0f);
    float e2 = __expf(2.0f * x);
    return (e2 - 1.0f) / (e2 + 1.0f);
}
__device__ __forceinline__ float lreluf(float x) { return x > 0.0f ? x : 0.01f * x; }
__device__ __forceinline__ unsigned short f2bf(float f) {
    unsigned int u = __float_as_uint(f);
    unsigned int r = (u + 0x7fffu + ((u >> 16) & 1u)) >> 16;
    return (unsigned short)r;
}
__device__ __forceinline__ float bf2f(unsigned short h) {
    return __uint_as_float(((unsigned int)h) << 16);
}
__device__ __forceinline__ f32x4 mfma16(bf16x8 a, bf16x8 b, f32x4 c) {
    return __builtin_amdgcn_mfma_f32_16x16x32_bf16(a, b, c, 0, 0, 0);
}

// ---------------- init: state=x0 (f32+bf16), h=0, out[0,:,0:32]=x0 ----------------
__global__ void init_kernel(const float* __restrict__ x0, float* __restrict__ state,
                            unsigned short* __restrict__ state_bf, unsigned short* __restrict__ hA,
                            float* __restrict__ out, int N)
{
    int i = blockIdx.x * 256 + threadIdx.x;
    if (i < N * HID) hA[i] = 0;
    if (i < N * IN_DIM) {
        float v = x0[i];
        state[i] = v;
        state_bf[i] = f2bf(v);
        int n = i >> 5, c = i & 31;
        out[(size_t)n * (2 * IN_DIM) + c] = v;
    }
}

// ---------------- prep: attention projection vectors + bias combine (1 block x 128) ----------------
__global__ void prep_kernel(const float* __restrict__ fc1, const float* __restrict__ attn1,
                            const float* __restrict__ fc2, const float* __restrict__ attn2,
                            const float* __restrict__ bih, const float* __restrict__ bhh,
                            float* __restrict__ va1, float* __restrict__ vd1,
                            float* __restrict__ va2, float* __restrict__ vd2,
                            float* __restrict__ br, float* __restrict__ bz,
                            float* __restrict__ bni, float* __restrict__ bnh)
{
    int j = threadIdx.x;  // 128
    float a1 = 0, d1 = 0, a2 = 0, d2 = 0;
    for (int c = 0; c < 128; ++c) {
        float w = fc1[c * HID + j];
        a1 += attn1[c] * w;
        d1 += attn1[128 + c] * w;
    }
    for (int c = 0; c < 32; ++c) {
        float w = fc2[c * HID + j];
        a2 += attn2[c] * w;
        d2 += attn2[32 + c] * w;
    }
    va1[j] = a1; vd1[j] = d1; va2[j] = a2; vd2[j] = d2;
    br[j]  = bih[j] + bhh[j];
    bz[j]  = bih[HID + j] + bhh[HID + j];
    bni[j] = bih[2 * HID + j];
    bnh[j] = bhh[2 * HID + j];
}

// ---------------- pack all weights into B-fragment order ----------------
// frag[((kc*NCT+ct)*64+lane)*8+j] = W_ext[c=ct*16+(lane&15)][k=kc*32+(lane>>4)*8+j]
#define NG (5 * 32 * 64 * 8)
#define N1 (4 * 9 * 64 * 8)
#define N2 (4 * 3 * 64 * 8)
__global__ void pack_all_kernel(const float* __restrict__ Wih, const float* __restrict__ Whh,
                                const float* __restrict__ fc1, const float* __restrict__ va1,
                                const float* __restrict__ vd1, const float* __restrict__ fc2,
                                const float* __restrict__ va2, const float* __restrict__ vd2,
                                unsigned short* __restrict__ Wg, unsigned short* __restrict__ F1p,
                                unsigned short* __restrict__ F2p)
{
    int idx = blockIdx.x * 256 + threadIdx.x;
    if (idx < NG) {
        int j = idx & 7, lane = (idx >> 3) & 63, tile = idx >> 9;
        int ct = tile & 31, kc = tile >> 5;
        int c = ct * 16 + (lane & 15);
        int k = kc * 32 + (lane >> 4) * 8 + j;
        float v;
        if (c < 256)      v = (k < 32) ? Wih[(size_t)c * 32 + k] : Whh[(size_t)c * 128 + (k - 32)];
        else if (c < 384) v = (k < 32) ? Wih[(size_t)c * 32 + k] : 0.0f;
        else              v = (k < 32) ? 0.0f : Whh[(size_t)(c - 128) * 128 + (k - 32)];
        Wg[idx] = f2bf(v);
    } else if (idx < NG + N1) {
        int i1 = idx - NG;
        int j = i1 & 7, lane = (i1 >> 3) & 63, tile = i1 >> 9;
        int ct = tile % 9, kc = tile / 9;
        int c = ct * 16 + (lane & 15);
        int k = kc * 32 + (lane >> 4) * 8 + j;
        float v;
        if (c < 128)       v = fc1[(size_t)c * 128 + k];
        else if (c == 128) v = va1[k];
        else if (c == 129) v = vd1[k];
        else               v = 0.0f;
        F1p[i1] = f2bf(v);
    } else if (idx < NG + N1 + N2) {
        int i2 = idx - NG - N1;
        int j = i2 & 7, lane = (i2 >> 3) & 63, tile = i2 >> 9;
        int ct = tile % 3, kc = tile / 3;
        int c = ct * 16 + (lane & 15);
        int k = kc * 32 + (lane >> 4) * 8 + j;
        float v;
        if (c < 32)       v = fc2[(size_t)c * 128 + k];
        else if (c == 32) v = va2[k];
        else if (c == 33) v = vd2[k];
        else              v = 0.0f;
        F2p[i2] = f2bf(v);
    }
}

// ---------------- KA: [gat2(t-1) + state update + out] + GRU + z1ext ----------------
__global__ __launch_bounds__(256)
void kA(const unsigned short* __restrict__ xbf, const unsigned short* __restrict__ hin,
        unsigned short* __restrict__ hout,
        const unsigned short* __restrict__ Wg, const unsigned short* __restrict__ Fc1,
        const float* __restrict__ br, const float* __restrict__ bz,
        const float* __restrict__ bni, const float* __restrict__ bnh,
        unsigned short* __restrict__ z1, float* __restrict__ ps1, float* __restrict__ pd1,
        const unsigned short* __restrict__ z2, const float* __restrict__ ps2,
        const float* __restrict__ pd2, const int* __restrict__ src,
        float* __restrict__ state, float* __restrict__ out, const float* __restrict__ tarr,
        int tstep, int N, int T)
{
    __shared__ unsigned short A[BM][APAD];   // [x | h_old], reused as z1 staging
    __shared__ unsigned short Ht[BM][HPAD];  // h_new

    const int tid = threadIdx.x, lane = tid & 63, w = tid >> 6;
    const int n0 = blockIdx.x * BM;
    const int row = lane & 15, kg = lane >> 4;
    const int mt = w & 1, ch = w >> 1;

    // stage h_old
    for (int idx = tid; idx < BM * 16; idx += 256) {
        int r = idx >> 4, seg = idx & 15, n = n0 + r;
        bf16x8 v = {0, 0, 0, 0, 0, 0, 0, 0};
        if (n < N) v = *(const bf16x8*)(hin + (size_t)n * HID + seg * 8);
        *(bf16x8*)&A[r][32 + seg * 8] = v;
    }

    if (tstep == 0) {
        // x-part from initial state
        for (int idx = tid; idx < BM * 4; idx += 256) {
            int r = idx >> 2, seg = idx & 3, n = n0 + r;
            bf16x8 v = {0, 0, 0, 0, 0, 0, 0, 0};
            if (n < N) v = *(const bf16x8*)(xbf + (size_t)n * IN_DIM + seg * 8);
            *(bf16x8*)&A[r][seg * 8] = v;
        }
    } else {
        // fused gat2 of step t-1: 8 nodes per wave
        float dt = tarr[tstep] - tarr[tstep - 1];
        #pragma unroll 1
        for (int it = 0; it < 8; ++it) {
            int iloc = w * 8 + it, i = n0 + iloc;
            bool valid = (i < N);
            int s = 0; float e = -3.0e38f;
            if (valid && lane < DEG) {
                s = src[i * DEG + lane];
                e = lreluf(ps2[s] + pd2[i]);
            }
            float m = e;
            m = fmaxf(m, __shfl_xor(m, 8));
            m = fmaxf(m, __shfl_xor(m, 4));
            m = fmaxf(m, __shfl_xor(m, 2));
            m = fmaxf(m, __shfl_xor(m, 1));
            float ee = (lane < DEG) ? __expf(e - m) : 0.0f;
            float sum = ee;
            sum += __shfl_xor(sum, 8);
            sum += __shfl_xor(sum, 4);
            sum += __shfl_xor(sum, 2);
            sum += __shfl_xor(sum, 1);
            float alpha = ee / sum;

            int c = lane & 31, eh = (lane >> 5) * 8;
            float acc = 0.0f;
            #pragma unroll
            for (int k = 0; k < 8; ++k) {
                float ak = __shfl(alpha, eh + k);
                int   sk = __shfl(s, eh + k);
                if (valid) acc = fmaf(ak, bf2f(z2[(size_t)sk * IN_DIM + c]), acc);
            }
            acc += __shfl_xor(acc, 32);
            if (valid && lane < 32) {
                float sv = state[(size_t)i * IN_DIM + c];
                float sn = fmaf(dt, acc, sv);
                state[(size_t)i * IN_DIM + c] = sn;
                size_t ob = ((size_t)(tstep - 1) * N + i) * (2 * IN_DIM);
                out[ob + IN_DIM + c] = acc;                       // xii_{t-1}
                out[ob + (size_t)N * (2 * IN_DIM) + c] = sn;      // out[t, 0:32]
                A[iloc][c] = f2bf(sn);
            }
        }
    }
    __syncthreads();

    // ---- GEMM1: gates[32 x 512], wave = (mt, ch): 4 ctqs x 4 gates ----
    #pragma unroll 1
    for (int q = 0; q < 4; ++q) {
        int ctq = ch * 4 + q;
        f32x4 acc0 = {0,0,0,0}, acc1 = {0,0,0,0}, acc2 = {0,0,0,0}, acc3 = {0,0,0,0};
        #pragma unroll
        for (int kc = 0; kc < 5; ++kc) {
            bf16x8 a = *(const bf16x8*)&A[mt * 16 + row][kc * 32 + kg * 8];
            const unsigned short* bp = Wg + ((size_t)(kc * 32 + ctq) * 64 + lane) * 8;
            bf16x8 b0 = *(const bf16x8*)(bp);
            bf16x8 b1 = *(const bf16x8*)(bp + (size_t)8  * 64 * 8);
            bf16x8 b2 = *(const bf16x8*)(bp + (size_t)16 * 64 * 8);
            bf16x8 b3 = *(const bf16x8*)(bp + (size_t)24 * 64 * 8);
            acc0 = mfma16(a, b0, acc0);
            acc1 = mfma16(a, b1, acc1);
            acc2 = mfma16(a, b2, acc2);
            acc3 = mfma16(a, b3, acc3);
        }
        int col = ctq * 16 + row;
        float brv = br[col], bzv = bz[col], bniv = bni[col], bnhv = bnh[col];
        #pragma unroll
        for (int rr = 0; rr < 4; ++rr) {
            int r_loc = mt * 16 + kg * 4 + rr;
            float rg = sigf(acc0[rr] + brv);
            float zg = sigf(acc1[rr] + bzv);
            float nc = tanhfast(acc2[rr] + bniv + rg * (acc3[rr] + bnhv));
            float hold = bf2f(A[r_loc][32 + col]);
            Ht[r_loc][col] = f2bf((1.0f - zg) * nc + zg * hold);
        }
    }
    __syncthreads();

    // h_new -> global (coalesced)
    for (int idx = tid; idx < BM * 16; idx += 256) {
        int r = idx >> 4, seg = idx & 15, n = n0 + r;
        if (n < N) *(bf16x8*)(hout + (size_t)n * HID + seg * 8) = *(const bf16x8*)&Ht[r][seg * 8];
    }

    // ---- GEMM2: z1ext[32 x 144], wave (mt,ch) does cts {ch, ch+2, ...} ----
    #pragma unroll 1
    for (int ct = ch; ct < 9; ct += 2) {
        f32x4 acc = {0, 0, 0, 0};
        #pragma unroll
        for (int kc = 0; kc < 4; ++kc) {
            bf16x8 a = *(const bf16x8*)&Ht[mt * 16 + row][kc * 32 + kg * 8];
            bf16x8 b = *(const bf16x8*)(Fc1 + ((size_t)(kc * 9 + ct) * 64 + lane) * 8);
            acc = mfma16(a, b, acc);
        }
        int col = ct * 16 + row;
        #pragma unroll
        for (int rr = 0; rr < 4; ++rr) {
            int r_loc = mt * 16 + kg * 4 + rr;
            int n = n0 + r_loc;
            if (col < 128)                  A[r_loc][col] = f2bf(acc[rr]);  // stage in LDS
            else if (n < N && col == 128)   ps1[n] = acc[rr];
            else if (n < N && col == 129)   pd1[n] = acc[rr];
        }
    }
    __syncthreads();

    // z1 -> global (coalesced)
    for (int idx = tid; idx < BM * 16; idx += 256) {
        int r = idx >> 4, seg = idx & 15, n = n0 + r;
        if (n < N) *(bf16x8*)(z1 + (size_t)n * HID + seg * 8) = *(const bf16x8*)&A[r][seg * 8];
    }
}

// ---------------- KB: gat1 aggregate + z2ext GEMM ----------------
__global__ __launch_bounds__(256)
void kB(const unsigned short* __restrict__ z1, const float* __restrict__ ps1,
        const float* __restrict__ pd1, const int* __restrict__ src,
        const unsigned short* __restrict__ Fc2,
        unsigned short* __restrict__ z2, float* __restrict__ ps2,
        float* __restrict__ pd2, int N)
{
    __shared__ unsigned short G[BM][HPAD];
    __shared__ unsigned short Z[BM][ZPAD];

    const int tid = threadIdx.x, lane = tid & 63, w = tid >> 6;
    const int n0 = blockIdx.x * BM;
    const int row = lane & 15, kg = lane >> 4;

    // phase 1: per wave 8 nodes: softmax over 16 in-edges + 128-col aggregate
    #pragma unroll 1
    for (int it = 0; it < 8; ++it) {
        int iloc = w * 8 + it, i = n0 + iloc;
        bool valid = (i < N);
        int s = 0; float e = -3.0e38f;
        if (valid && lane < DEG) {
            s = src[i * DEG + lane];
            e = lreluf(ps1[s] + pd1[i]);
        }
        float m = e;
        m = fmaxf(m, __shfl_xor(m, 8));
        m = fmaxf(m, __shfl_xor(m, 4));
        m = fmaxf(m, __shfl_xor(m, 2));
        m = fmaxf(m, __shfl_xor(m, 1));
        float ee = (lane < DEG) ? __expf(e - m) : 0.0f;
        float sum = ee;
        sum += __shfl_xor(sum, 8);
        sum += __shfl_xor(sum, 4);
        sum += __shfl_xor(sum, 2);
        sum += __shfl_xor(sum, 1);
        float alpha = ee / sum;

        int sks[DEG];
        float als[DEG];
        #pragma unroll
        for (int k = 0; k < DEG; ++k) {
            sks[k] = __shfl(s, k);
            als[k] = __shfl(alpha, k);
        }
        float a0 = 0.0f, a1 = 0.0f;
        const int c2 = lane * 2;
        if (valid) {
            unsigned int vv[DEG];
            #pragma unroll
            for (int k = 0; k < DEG; ++k)
                vv[k] = *(const unsigned int*)(z1 + (size_t)sks[k] * HID + c2);
            #pragma unroll
            for (int k = 0; k < DEG; ++k) {
                a0 = fmaf(als[k], __uint_as_float((vv[k] & 0xffffu) << 16), a0);
                a1 = fmaf(als[k], __uint_as_float(vv[k] & 0xffff0000u), a1);
            }
        }
        G[iloc][c2]     = f2bf(fmaxf(a0, 0.0f));
        G[iloc][c2 + 1] = f2bf(fmaxf(a1, 0.0f));
    }
    __syncthreads();

    // phase 2: z2ext[32 x 48]; 6 tiles over 4 waves
    #pragma unroll 1
    for (int tau = w; tau < 6; tau += 4) {
        int mtt = tau / 3, ct = tau % 3;
        f32x4 acc = {0, 0, 0, 0};
        #pragma unroll
        for (int kc = 0; kc < 4; ++kc) {
            bf16x8 a = *(const bf16x8*)&G[mtt * 16 + row][kc * 32 + kg * 8];
            bf16x8 b = *(const bf16x8*)(Fc2 + ((size_t)(kc * 3 + ct) * 64 + lane) * 8);
            acc = mfma16(a, b, acc);
        }
        int col = ct * 16 + row;
        #pragma unroll
        for (int rr = 0; rr < 4; ++rr) {
            int r_loc = mtt * 16 + kg * 4 + rr;
            int n = n0 + r_loc;
            if (col < 32)                 Z[r_loc][col] = f2bf(acc[rr]);
            else if (n < N && col == 32)  ps2[n] = acc[rr];
            else if (n < N && col == 33)  pd2[n] = acc[rr];
        }
    }
    __syncthreads();

    for (int idx = tid; idx < BM * 4; idx += 256) {
        int r = idx >> 2, seg = idx & 3, n = n0 + r;
        if (n < N) *(bf16x8*)(z2 + (size_t)n * IN_DIM + seg * 8) = *(const bf16x8*)&Z[r][seg * 8];
    }
}

// ---------------- tail: gat2 for t = T-1 (xii only, no state update) ----------------
__global__ __launch_bounds__(256)
void kTail(const unsigned short* __restrict__ z2, const float* __restrict__ ps2,
           const float* __restrict__ pd2, const int* __restrict__ src,
           float* __restrict__ out, int N, int T)
{
    const int lane = threadIdx.x & 63;
    const int i = blockIdx.x * 4 + (threadIdx.x >> 6);
    if (i >= N) return;

    int s = 0; float e = -3.0e38f;
    if (lane < DEG) {
        s = src[i * DEG + lane];
        e = lreluf(ps2[s] + pd2[i]);
    }
    float m = e;
    m = fmaxf(m, __shfl_xor(m, 8));
    m = fmaxf(m, __shfl_xor(m, 4));
    m = fmaxf(m, __shfl_xor(m, 2));
    m = fmaxf(m, __shfl_xor(m, 1));
    float ee = (lane < DEG) ? __expf(e - m) : 0.0f;
    float sum = ee;
    sum += __shfl_xor(sum, 8);
    sum += __shfl_xor(sum, 4);
    sum += __shfl_xor(sum, 2);
    sum += __shfl_xor(sum, 1);
    float alpha = ee / sum;

    const int cl = lane & (IN_DIM - 1);
    float acc = 0.0f;
    #pragma unroll
    for (int k = 0; k < DEG; ++k) {
        float ak = __shfl(alpha, k);
        int   sk = __shfl(s, k);
        acc = fmaf(ak, bf2f(z2[(size_t)sk * IN_DIM + cl]), acc);
    }
    if (lane < IN_DIM) {
        size_t ob = ((size_t)(T - 1) * N + i) * (2 * IN_DIM);
        out[ob + IN_DIM + lane] = acc;
    }
}

extern "C" void kernel_launch(void* const* d_in, const int* in_sizes, int n_in,
                              void* d_out, int out_size, void* d_ws, size_t ws_size,
                              hipStream_t stream)
{
    const float* tarr  = (const float*)d_in[0];
    const float* x0    = (const float*)d_in[1];
    const int*   src   = (const int*)d_in[2];
    // d_in[3] = dst (structural: repeat(arange(N), DEG))
    const float* Wih   = (const float*)d_in[4];
    const float* Whh   = (const float*)d_in[5];
    const float* bih   = (const float*)d_in[6];
    const float* bhh   = (const float*)d_in[7];
    const float* fc1   = (const float*)d_in[8];
    const float* attn1 = (const float*)d_in[9];
    const float* fc2   = (const float*)d_in[10];
    const float* attn2 = (const float*)d_in[11];
    float* out = (float*)d_out;

    const int T = in_sizes[0];
    const int N = in_sizes[1] / IN_DIM;

    // f32 region
    float* fp = (float*)d_ws;
    float* state = fp; fp += (size_t)N * IN_DIM;
    float* ps1 = fp; fp += N;
    float* pd1 = fp; fp += N;
    float* ps2 = fp; fp += N;
    float* pd2 = fp; fp += N;
    float* va1 = fp; fp += HID;
    float* vd1 = fp; fp += HID;
    float* va2 = fp; fp += HID;
    float* vd2 = fp; fp += HID;
    float* br  = fp; fp += HID;
    float* bz  = fp; fp += HID;
    float* bni = fp; fp += HID;
    float* bnh = fp; fp += HID;
    // bf16 region
    unsigned short* up = (unsigned short*)fp;
    unsigned short* state_bf = up; up += (size_t)N * IN_DIM;
    unsigned short* hA  = up; up += (size_t)N * HID;
    unsigned short* hB  = up; up += (size_t)N * HID;
    unsigned short* z1  = up; up += (size_t)N * HID;
    unsigned short* z2  = up; up += (size_t)N * IN_DIM;
    unsigned short* Wg  = up; up += NG;
    unsigned short* F1p = up; up += N1;
    unsigned short* F2p = up; up += N2;

    const int nblk = (N + BM - 1) / BM;

    init_kernel<<<(N * HID + 255) / 256, 256, 0, stream>>>(x0, state, state_bf, hA, out, N);
    prep_kernel<<<1, 128, 0, stream>>>(fc1, attn1, fc2, attn2, bih, bhh,
                                       va1, vd1, va2, vd2, br, bz, bni, bnh);
    pack_all_kernel<<<(NG + N1 + N2 + 255) / 256, 256, 0, stream>>>(
        Wih, Whh, fc1, va1, vd1, fc2, va2, vd2, Wg, F1p, F2p);

    for (int t = 0; t < T; ++t) {
        const unsigned short* hin  = (t & 1) ? hB : hA;
        unsigned short*       houtp = (t & 1) ? hA : hB;

        kA<<<nblk, 256, 0, stream>>>(state_bf, hin, houtp, Wg, F1p,
                                     br, bz, bni, bnh, z1, ps1, pd1,
                                     z2, ps2, pd2, src, state, out, tarr, t, N, T);
        kB<<<nblk, 256, 0, stream>>>(z1, ps1, pd1, src, F2p, z2, ps2, pd2, N);
    }
    kTail<<<(N + 3) / 4, 256, 0, stream>>>(z2, ps2, pd2, src, out, N, T);
}

// Round 5
// 664.064 us; speedup vs baseline: 6.9407x; 1.7442x over previous
//
#include <hip/hip_runtime.h>

#define IN_DIM 32
#define HID 128
#define DEG 16
#define BM 32
#define APAD 168   // A-tile row stride (ushorts)
#define HPAD 136   // h-tile row stride
#define ZPAD 40    // z2-stage row stride

typedef short bf16x8 __attribute__((ext_vector_type(8)));
typedef float f32x4 __attribute__((ext_vector_type(4)));

__device__ __forceinline__ float sigf(float x)   { return 1.0f / (1.0f + __expf(-x)); }
__device__ __forceinline__ float tanhfast(float x) {
    x = fminf(fmaxf(x, -15.0f), 15.0f);
    float e2 = __expf(2.0f * x);
    return (e2 - 1.0f) / (e2 + 1.0f);
}
__device__ __forceinline__ float lreluf(float x) { return x > 0.0f ? x : 0.01f * x; }
__device__ __forceinline__ unsigned short f2bf(float f) {
    unsigned int u = __float_as_uint(f);
    unsigned int r = (u + 0x7fffu + ((u >> 16) & 1u)) >> 16;
    return (unsigned short)r;
}
__device__ __forceinline__ float bf2f(unsigned short h) {
    return __uint_as_float(((unsigned int)h) << 16);
}
__device__ __forceinline__ float bflo(unsigned int v) {
    return __uint_as_float((v & 0xffffu) << 16);
}
__device__ __forceinline__ float bfhi(unsigned int v) {
    return __uint_as_float(v & 0xffff0000u);
}
__device__ __forceinline__ f32x4 mfma16(bf16x8 a, bf16x8 b, f32x4 c) {
    return __builtin_amdgcn_mfma_f32_16x16x32_bf16(a, b, c, 0, 0, 0);
}

// ---------------- init: state=x0 (f32+bf16), h=0, out[0,:,0:32]=x0 ----------------
__global__ void init_kernel(const float* __restrict__ x0, float* __restrict__ state,
                            unsigned short* __restrict__ state_bf, unsigned short* __restrict__ hA,
                            float* __restrict__ out, int N)
{
    int i = blockIdx.x * 256 + threadIdx.x;
    if (i < N * HID) hA[i] = 0;
    if (i < N * IN_DIM) {
        float v = x0[i];
        state[i] = v;
        state_bf[i] = f2bf(v);
        int n = i >> 5, c = i & 31;
        out[(size_t)n * (2 * IN_DIM) + c] = v;
    }
}

// ---------------- prep: attention projection vectors + bias combine ----------------
__global__ void prep_kernel(const float* __restrict__ fc1, const float* __restrict__ attn1,
                            const float* __restrict__ fc2, const float* __restrict__ attn2,
                            const float* __restrict__ bih, const float* __restrict__ bhh,
                            float* __restrict__ va1, float* __restrict__ vd1,
                            float* __restrict__ va2, float* __restrict__ vd2,
                            float* __restrict__ br, float* __restrict__ bz,
                            float* __restrict__ bni, float* __restrict__ bnh)
{
    int j = threadIdx.x;  // 128
    float a1 = 0, d1 = 0, a2 = 0, d2 = 0;
    for (int c = 0; c < 128; ++c) {
        float w = fc1[c * HID + j];
        a1 += attn1[c] * w;
        d1 += attn1[128 + c] * w;
    }
    for (int c = 0; c < 32; ++c) {
        float w = fc2[c * HID + j];
        a2 += attn2[c] * w;
        d2 += attn2[32 + c] * w;
    }
    va1[j] = a1; vd1[j] = d1; va2[j] = a2; vd2[j] = d2;
    br[j]  = bih[j] + bhh[j];
    bz[j]  = bih[HID + j] + bhh[HID + j];
    bni[j] = bih[2 * HID + j];
    bnh[j] = bhh[2 * HID + j];
}

// ---------------- pack all weights into B-fragment order ----------------
#define NG (5 * 32 * 64 * 8)
#define N1 (4 * 9 * 64 * 8)
#define N2 (4 * 3 * 64 * 8)
__global__ void pack_all_kernel(const float* __restrict__ Wih, const float* __restrict__ Whh,
                                const float* __restrict__ fc1, const float* __restrict__ va1,
                                const float* __restrict__ vd1, const float* __restrict__ fc2,
                                const float* __restrict__ va2, const float* __restrict__ vd2,
                                unsigned short* __restrict__ Wg, unsigned short* __restrict__ F1p,
                                unsigned short* __restrict__ F2p)
{
    int idx = blockIdx.x * 256 + threadIdx.x;
    if (idx < NG) {
        int j = idx & 7, lane = (idx >> 3) & 63, tile = idx >> 9;
        int ct = tile & 31, kc = tile >> 5;
        int c = ct * 16 + (lane & 15);
        int k = kc * 32 + (lane >> 4) * 8 + j;
        float v;
        if (c < 256)      v = (k < 32) ? Wih[(size_t)c * 32 + k] : Whh[(size_t)c * 128 + (k - 32)];
        else if (c < 384) v = (k < 32) ? Wih[(size_t)c * 32 + k] : 0.0f;
        else              v = (k < 32) ? 0.0f : Whh[(size_t)(c - 128) * 128 + (k - 32)];
        Wg[idx] = f2bf(v);
    } else if (idx < NG + N1) {
        int i1 = idx - NG;
        int j = i1 & 7, lane = (i1 >> 3) & 63, tile = i1 >> 9;
        int ct = tile % 9, kc = tile / 9;
        int c = ct * 16 + (lane & 15);
        int k = kc * 32 + (lane >> 4) * 8 + j;
        float v;
        if (c < 128)       v = fc1[(size_t)c * 128 + k];
        else if (c == 128) v = va1[k];
        else if (c == 129) v = vd1[k];
        else               v = 0.0f;
        F1p[i1] = f2bf(v);
    } else if (idx < NG + N1 + N2) {
        int i2 = idx - NG - N1;
        int j = i2 & 7, lane = (i2 >> 3) & 63, tile = i2 >> 9;
        int ct = tile % 3, kc = tile / 3;
        int c = ct * 16 + (lane & 15);
        int k = kc * 32 + (lane >> 4) * 8 + j;
        float v;
        if (c < 32)       v = fc2[(size_t)c * 128 + k];
        else if (c == 32) v = va2[k];
        else if (c == 33) v = vd2[k];
        else              v = 0.0f;
        F2p[i2] = f2bf(v);
    }
}

// ---------------- KA: [gat2(t-1) + state update + out] + GRU + z1ext (512 thr) ----------------
__global__ __launch_bounds__(512)
void kA(const unsigned short* __restrict__ xbf, const unsigned short* __restrict__ hin,
        unsigned short* __restrict__ hout,
        const unsigned short* __restrict__ Wg, const unsigned short* __restrict__ Fc1,
        const float* __restrict__ br, const float* __restrict__ bz,
        const float* __restrict__ bni, const float* __restrict__ bnh,
        unsigned short* __restrict__ z1, float* __restrict__ ps1, float* __restrict__ pd1,
        const unsigned short* __restrict__ z2, const float* __restrict__ ps2,
        const float* __restrict__ pd2, const int* __restrict__ src,
        float* __restrict__ state, float* __restrict__ out, const float* __restrict__ tarr,
        int tstep, int N, int T)
{
    __shared__ unsigned short A[BM][APAD];   // [x | h_old], later z1 staging
    __shared__ unsigned short Ht[BM][HPAD];  // h_new
    __shared__ int   sE[BM][DEG];
    __shared__ float aE[BM][DEG];

    const int tid = threadIdx.x, lane = tid & 63, w = tid >> 6;
    const int n0 = blockIdx.x * BM;
    const int row = lane & 15, kg = lane >> 4;
    const int mt = w & 1, ch = w >> 1;
    const int rn = tid >> 4, le = tid & 15;   // node-local / edge-or-colslice

    // stage h_old: one bf16x8 per thread
    {
        int n = n0 + rn;
        bf16x8 v = {0, 0, 0, 0, 0, 0, 0, 0};
        if (n < N) v = *(const bf16x8*)(hin + (size_t)n * HID + le * 8);
        *(bf16x8*)&A[rn][32 + le * 8] = v;
    }

    if (tstep == 0) {
        if (tid < BM * 4) {
            int r = tid >> 2, seg = tid & 3, n = n0 + r;
            bf16x8 v = {0, 0, 0, 0, 0, 0, 0, 0};
            if (n < N) v = *(const bf16x8*)(xbf + (size_t)n * IN_DIM + seg * 8);
            *(bf16x8*)&A[r][seg * 8] = v;
        }
    } else {
        // ---- fused gat2 of step t-1 ----
        // scores: 1 edge per thread
        {
            int i = n0 + rn;
            int s = 0; float e = -3.0e38f;
            if (i < N) {
                s = src[i * DEG + le];
                e = lreluf(ps2[s] + pd2[i]);
            }
            float m = e;
            m = fmaxf(m, __shfl_xor(m, 8));
            m = fmaxf(m, __shfl_xor(m, 4));
            m = fmaxf(m, __shfl_xor(m, 2));
            m = fmaxf(m, __shfl_xor(m, 1));
            float ee = __expf(e - m);
            float sum = ee;
            sum += __shfl_xor(sum, 8);
            sum += __shfl_xor(sum, 4);
            sum += __shfl_xor(sum, 2);
            sum += __shfl_xor(sum, 1);
            sE[rn][le] = s;
            aE[rn][le] = ee / sum;
        }
        __syncthreads();
        // aggregate: thread = (node rn, cols c2..c2+1)
        {
            const int c2 = le * 2;
            float a0 = 0.0f, a1 = 0.0f;
            #pragma unroll
            for (int k = 0; k < DEG; ++k) {
                int   s = sE[rn][k];       // LDS broadcast
                float a = aE[rn][k];
                unsigned int v = *(const unsigned int*)(z2 + (size_t)s * IN_DIM + c2);
                a0 = fmaf(a, bflo(v), a0);
                a1 = fmaf(a, bfhi(v), a1);
            }
            int i = n0 + rn;
            if (i < N) {
                float dt = tarr[tstep] - tarr[tstep - 1];
                float sv0 = state[(size_t)i * IN_DIM + c2];
                float sv1 = state[(size_t)i * IN_DIM + c2 + 1];
                float sn0 = fmaf(dt, a0, sv0);
                float sn1 = fmaf(dt, a1, sv1);
                state[(size_t)i * IN_DIM + c2]     = sn0;
                state[(size_t)i * IN_DIM + c2 + 1] = sn1;
                size_t ob = ((size_t)(tstep - 1) * N + i) * (2 * IN_DIM);
                out[ob + IN_DIM + c2]     = a0;
                out[ob + IN_DIM + c2 + 1] = a1;
                out[ob + (size_t)N * (2 * IN_DIM) + c2]     = sn0;
                out[ob + (size_t)N * (2 * IN_DIM) + c2 + 1] = sn1;
                A[rn][c2]     = f2bf(sn0);
                A[rn][c2 + 1] = f2bf(sn1);
            }
        }
    }
    __syncthreads();

    // ---- GEMM1: gates[32 x 512]; wave (mt, ch) does ctq = ch*2 + q ----
    #pragma unroll 1
    for (int q = 0; q < 2; ++q) {
        int ctq = ch * 2 + q;
        f32x4 acc0 = {0,0,0,0}, acc1 = {0,0,0,0}, acc2 = {0,0,0,0}, acc3 = {0,0,0,0};
        #pragma unroll
        for (int kc = 0; kc < 5; ++kc) {
            bf16x8 a = *(const bf16x8*)&A[mt * 16 + row][kc * 32 + kg * 8];
            const unsigned short* bp = Wg + ((size_t)(kc * 32 + ctq) * 64 + lane) * 8;
            bf16x8 b0 = *(const bf16x8*)(bp);
            bf16x8 b1 = *(const bf16x8*)(bp + (size_t)8  * 64 * 8);
            bf16x8 b2 = *(const bf16x8*)(bp + (size_t)16 * 64 * 8);
            bf16x8 b3 = *(const bf16x8*)(bp + (size_t)24 * 64 * 8);
            acc0 = mfma16(a, b0, acc0);
            acc1 = mfma16(a, b1, acc1);
            acc2 = mfma16(a, b2, acc2);
            acc3 = mfma16(a, b3, acc3);
        }
        int col = ctq * 16 + row;
        float brv = br[col], bzv = bz[col], bniv = bni[col], bnhv = bnh[col];
        #pragma unroll
        for (int rr = 0; rr < 4; ++rr) {
            int r_loc = mt * 16 + kg * 4 + rr;
            float rg = sigf(acc0[rr] + brv);
            float zg = sigf(acc1[rr] + bzv);
            float nc = tanhfast(acc2[rr] + bniv + rg * (acc3[rr] + bnhv));
            float hold = bf2f(A[r_loc][32 + col]);
            Ht[r_loc][col] = f2bf((1.0f - zg) * nc + zg * hold);
        }
    }
    __syncthreads();

    // h_new -> global: one bf16x8 per thread
    {
        int n = n0 + rn;
        if (n < N) *(bf16x8*)(hout + (size_t)n * HID + le * 8) = *(const bf16x8*)&Ht[rn][le * 8];
    }

    // ---- GEMM2: z1ext[32 x 144]; 18 tiles over 8 waves ----
    #pragma unroll 1
    for (int tau = w; tau < 18; tau += 8) {
        int mtt = tau / 9, ct = tau % 9;
        f32x4 acc = {0, 0, 0, 0};
        #pragma unroll
        for (int kc = 0; kc < 4; ++kc) {
            bf16x8 a = *(const bf16x8*)&Ht[mtt * 16 + row][kc * 32 + kg * 8];
            bf16x8 b = *(const bf16x8*)(Fc1 + ((size_t)(kc * 9 + ct) * 64 + lane) * 8);
            acc = mfma16(a, b, acc);
        }
        int col = ct * 16 + row;
        #pragma unroll
        for (int rr = 0; rr < 4; ++rr) {
            int r_loc = mtt * 16 + kg * 4 + rr;
            int n = n0 + r_loc;
            if (col < 128)                A[r_loc][col] = f2bf(acc[rr]);
            else if (n < N && col == 128) ps1[n] = acc[rr];
            else if (n < N && col == 129) pd1[n] = acc[rr];
        }
    }
    __syncthreads();

    // z1 -> global
    {
        int n = n0 + rn;
        if (n < N) *(bf16x8*)(z1 + (size_t)n * HID + le * 8) = *(const bf16x8*)&A[rn][le * 8];
    }
}

// ---------------- KB: gat1 aggregate + z2ext GEMM (512 thr) ----------------
__global__ __launch_bounds__(512)
void kB(const unsigned short* __restrict__ z1, const float* __restrict__ ps1,
        const float* __restrict__ pd1, const int* __restrict__ src,
        const unsigned short* __restrict__ Fc2,
        unsigned short* __restrict__ z2, float* __restrict__ ps2,
        float* __restrict__ pd2, int N)
{
    __shared__ unsigned short G[BM][HPAD];
    __shared__ unsigned short Z[BM][ZPAD];
    __shared__ int   sE[BM][DEG];
    __shared__ float aE[BM][DEG];

    const int tid = threadIdx.x, lane = tid & 63, w = tid >> 6;
    const int n0 = blockIdx.x * BM;
    const int row = lane & 15, kg = lane >> 4;
    const int rn = tid >> 4, le = tid & 15;

    // scores: 1 edge per thread
    {
        int i = n0 + rn;
        int s = 0; float e = -3.0e38f;
        if (i < N) {
            s = src[i * DEG + le];
            e = lreluf(ps1[s] + pd1[i]);
        }
        float m = e;
        m = fmaxf(m, __shfl_xor(m, 8));
        m = fmaxf(m, __shfl_xor(m, 4));
        m = fmaxf(m, __shfl_xor(m, 2));
        m = fmaxf(m, __shfl_xor(m, 1));
        float ee = __expf(e - m);
        float sum = ee;
        sum += __shfl_xor(sum, 8);
        sum += __shfl_xor(sum, 4);
        sum += __shfl_xor(sum, 2);
        sum += __shfl_xor(sum, 1);
        sE[rn][le] = s;
        aE[rn][le] = ee / sum;
    }
    __syncthreads();

    // aggregate: thread = (node rn, cols le*8 .. le*8+7); per edge 16B coalesced
    {
        const int c8 = le * 8;
        float ac[8] = {0, 0, 0, 0, 0, 0, 0, 0};
        #pragma unroll
        for (int k = 0; k < DEG; ++k) {
            int   s = sE[rn][k];
            float a = aE[rn][k];
            const unsigned int* zp = (const unsigned int*)(z1 + (size_t)s * HID + c8);
            unsigned int v0 = zp[0], v1 = zp[1], v2 = zp[2], v3 = zp[3];
            ac[0] = fmaf(a, bflo(v0), ac[0]);
            ac[1] = fmaf(a, bfhi(v0), ac[1]);
            ac[2] = fmaf(a, bflo(v1), ac[2]);
            ac[3] = fmaf(a, bfhi(v1), ac[3]);
            ac[4] = fmaf(a, bflo(v2), ac[4]);
            ac[5] = fmaf(a, bfhi(v2), ac[5]);
            ac[6] = fmaf(a, bflo(v3), ac[6]);
            ac[7] = fmaf(a, bfhi(v3), ac[7]);
        }
        #pragma unroll
        for (int j = 0; j < 8; ++j) G[rn][c8 + j] = f2bf(fmaxf(ac[j], 0.0f));
    }
    __syncthreads();

    // z2ext[32 x 48]: 6 tiles over 8 waves
    #pragma unroll 1
    for (int tau = w; tau < 6; tau += 8) {
        int mtt = tau / 3, ct = tau % 3;
        f32x4 acc = {0, 0, 0, 0};
        #pragma unroll
        for (int kc = 0; kc < 4; ++kc) {
            bf16x8 a = *(const bf16x8*)&G[mtt * 16 + row][kc * 32 + kg * 8];
            bf16x8 b = *(const bf16x8*)(Fc2 + ((size_t)(kc * 3 + ct) * 64 + lane) * 8);
            acc = mfma16(a, b, acc);
        }
        int col = ct * 16 + row;
        #pragma unroll
        for (int rr = 0; rr < 4; ++rr) {
            int r_loc = mtt * 16 + kg * 4 + rr;
            int n = n0 + r_loc;
            if (col < 32)                Z[r_loc][col] = f2bf(acc[rr]);
            else if (n < N && col == 32) ps2[n] = acc[rr];
            else if (n < N && col == 33) pd2[n] = acc[rr];
        }
    }
    __syncthreads();

    if (tid < BM * 4) {
        int r = tid >> 2, seg = tid & 3, n = n0 + r;
        if (n < N) *(bf16x8*)(z2 + (size_t)n * IN_DIM + seg * 8) = *(const bf16x8*)&Z[r][seg * 8];
    }
}

// ---------------- tail: gat2 for t = T-1 (xii only) ----------------
__global__ __launch_bounds__(512)
void kTail(const unsigned short* __restrict__ z2, const float* __restrict__ ps2,
           const float* __restrict__ pd2, const int* __restrict__ src,
           float* __restrict__ out, int N, int T)
{
    __shared__ int   sE[BM][DEG];
    __shared__ float aE[BM][DEG];
    const int tid = threadIdx.x;
    const int n0 = blockIdx.x * BM;
    const int rn = tid >> 4, le = tid & 15;

    {
        int i = n0 + rn;
        int s = 0; float e = -3.0e38f;
        if (i < N) {
            s = src[i * DEG + le];
            e = lreluf(ps2[s] + pd2[i]);
        }
        float m = e;
        m = fmaxf(m, __shfl_xor(m, 8));
        m = fmaxf(m, __shfl_xor(m, 4));
        m = fmaxf(m, __shfl_xor(m, 2));
        m = fmaxf(m, __shfl_xor(m, 1));
        float ee = __expf(e - m);
        float sum = ee;
        sum += __shfl_xor(sum, 8);
        sum += __shfl_xor(sum, 4);
        sum += __shfl_xor(sum, 2);
        sum += __shfl_xor(sum, 1);
        sE[rn][le] = s;
        aE[rn][le] = ee / sum;
    }
    __syncthreads();

    {
        const int c2 = le * 2;
        float a0 = 0.0f, a1 = 0.0f;
        #pragma unroll
        for (int k = 0; k < DEG; ++k) {
            int   s = sE[rn][k];
            float a = aE[rn][k];
            unsigned int v = *(const unsigned int*)(z2 + (size_t)s * IN_DIM + c2);
            a0 = fmaf(a, bflo(v), a0);
            a1 = fmaf(a, bfhi(v), a1);
        }
        int i = n0 + rn;
        if (i < N) {
            size_t ob = ((size_t)(T - 1) * N + i) * (2 * IN_DIM);
            out[ob + IN_DIM + c2]     = a0;
            out[ob + IN_DIM + c2 + 1] = a1;
        }
    }
}

extern "C" void kernel_launch(void* const* d_in, const int* in_sizes, int n_in,
                              void* d_out, int out_size, void* d_ws, size_t ws_size,
                              hipStream_t stream)
{
    const float* tarr  = (const float*)d_in[0];
    const float* x0    = (const float*)d_in[1];
    const int*   src   = (const int*)d_in[2];
    // d_in[3] = dst (structural: repeat(arange(N), DEG))
    const float* Wih   = (const float*)d_in[4];
    const float* Whh   = (const float*)d_in[5];
    const float* bih   = (const float*)d_in[6];
    const float* bhh   = (const float*)d_in[7];
    const float* fc1   = (const float*)d_in[8];
    const float* attn1 = (const float*)d_in[9];
    const float* fc2   = (const float*)d_in[10];
    const float* attn2 = (const float*)d_in[11];
    float* out = (float*)d_out;

    const int T = in_sizes[0];
    const int N = in_sizes[1] / IN_DIM;

    // f32 region
    float* fp = (float*)d_ws;
    float* state = fp; fp += (size_t)N * IN_DIM;
    float* ps1 = fp; fp += N;
    float* pd1 = fp; fp += N;
    float* ps2 = fp; fp += N;
    float* pd2 = fp; fp += N;
    float* va1 = fp; fp += HID;
    float* vd1 = fp; fp += HID;
    float* va2 = fp; fp += HID;
    float* vd2 = fp; fp += HID;
    float* br  = fp; fp += HID;
    float* bz  = fp; fp += HID;
    float* bni = fp; fp += HID;
    float* bnh = fp; fp += HID;
    // bf16 region
    unsigned short* up = (unsigned short*)fp;
    unsigned short* state_bf = up; up += (size_t)N * IN_DIM;
    unsigned short* hA  = up; up += (size_t)N * HID;
    unsigned short* hB  = up; up += (size_t)N * HID;
    unsigned short* z1  = up; up += (size_t)N * HID;
    unsigned short* z2  = up; up += (size_t)N * IN_DIM;
    unsigned short* Wg  = up; up += NG;
    unsigned short* F1p = up; up += N1;
    unsigned short* F2p = up; up += N2;

    const int nblk = (N + BM - 1) / BM;

    init_kernel<<<(N * HID + 255) / 256, 256, 0, stream>>>(x0, state, state_bf, hA, out, N);
    prep_kernel<<<1, 128, 0, stream>>>(fc1, attn1, fc2, attn2, bih, bhh,
                                       va1, vd1, va2, vd2, br, bz, bni, bnh);
    pack_all_kernel<<<(NG + N1 + N2 + 255) / 256, 256, 0, stream>>>(
        Wih, Whh, fc1, va1, vd1, fc2, va2, vd2, Wg, F1p, F2p);

    for (int t = 0; t < T; ++t) {
        const unsigned short* hin   = (t & 1) ? hB : hA;
        unsigned short*       houtp = (t & 1) ? hA : hB;

        kA<<<nblk, 512, 0, stream>>>(state_bf, hin, houtp, Wg, F1p,
                                     br, bz, bni, bnh, z1, ps1, pd1,
                                     z2, ps2, pd2, src, state, out, tarr, t, N, T);
        kB<<<nblk, 512, 0, stream>>>(z1, ps1, pd1, src, F2p, z2, ps2, pd2, N);
    }
    kTail<<<nblk, 512, 0, stream>>>(z2, ps2, pd2, src, out, N, T);
}

// Round 6
// 650.889 us; speedup vs baseline: 7.0812x; 1.0202x over previous
//
#include <hip/hip_runtime.h>

#define IN_DIM 32
#define HID 128
#define DEG 16
#define BM 16
#define APAD 168   // A-tile row stride (ushorts)
#define HPAD 136   // h-tile row stride
#define ZPAD 40    // z2-stage row stride

typedef short bf16x8 __attribute__((ext_vector_type(8)));
typedef float f32x4 __attribute__((ext_vector_type(4)));

__device__ __forceinline__ float sigf(float x)   { return 1.0f / (1.0f + __expf(-x)); }
__device__ __forceinline__ float tanhfast(float x) {
    x = fminf(fmaxf(x, -15.0f), 15.0f);
    float e2 = __expf(2.0f * x);
    return (e2 - 1.0f) / (e2 + 1.0f);
}
__device__ __forceinline__ float lreluf(float x) { return x > 0.0f ? x : 0.01f * x; }
__device__ __forceinline__ unsigned short f2bf(float f) {
    unsigned int u = __float_as_uint(f);
    unsigned int r = (u + 0x7fffu + ((u >> 16) & 1u)) >> 16;
    return (unsigned short)r;
}
__device__ __forceinline__ float bf2f(unsigned short h) {
    return __uint_as_float(((unsigned int)h) << 16);
}
__device__ __forceinline__ float bflo(unsigned int v) {
    return __uint_as_float((v & 0xffffu) << 16);
}
__device__ __forceinline__ float bfhi(unsigned int v) {
    return __uint_as_float(v & 0xffff0000u);
}
__device__ __forceinline__ f32x4 mfma16(bf16x8 a, bf16x8 b, f32x4 c) {
    return __builtin_amdgcn_mfma_f32_16x16x32_bf16(a, b, c, 0, 0, 0);
}

// ---------------- init: state=x0 (f32+bf16), h=0, out[0,:,0:32]=x0 ----------------
__global__ void init_kernel(const float* __restrict__ x0, float* __restrict__ state,
                            unsigned short* __restrict__ state_bf, unsigned short* __restrict__ hA,
                            float* __restrict__ out, int N)
{
    int i = blockIdx.x * 256 + threadIdx.x;
    if (i < N * HID) hA[i] = 0;
    if (i < N * IN_DIM) {
        float v = x0[i];
        state[i] = v;
        state_bf[i] = f2bf(v);
        int n = i >> 5, c = i & 31;
        out[(size_t)n * (2 * IN_DIM) + c] = v;
    }
}

// ---------------- prep: attention projection vectors + bias combine ----------------
__global__ void prep_kernel(const float* __restrict__ fc1, const float* __restrict__ attn1,
                            const float* __restrict__ fc2, const float* __restrict__ attn2,
                            const float* __restrict__ bih, const float* __restrict__ bhh,
                            float* __restrict__ va1, float* __restrict__ vd1,
                            float* __restrict__ va2, float* __restrict__ vd2,
                            float* __restrict__ br, float* __restrict__ bz,
                            float* __restrict__ bni, float* __restrict__ bnh)
{
    int j = threadIdx.x;  // 128
    float a1 = 0, d1 = 0, a2 = 0, d2 = 0;
    for (int c = 0; c < 128; ++c) {
        float w = fc1[c * HID + j];
        a1 += attn1[c] * w;
        d1 += attn1[128 + c] * w;
    }
    for (int c = 0; c < 32; ++c) {
        float w = fc2[c * HID + j];
        a2 += attn2[c] * w;
        d2 += attn2[32 + c] * w;
    }
    va1[j] = a1; vd1[j] = d1; va2[j] = a2; vd2[j] = d2;
    br[j]  = bih[j] + bhh[j];
    bz[j]  = bih[HID + j] + bhh[HID + j];
    bni[j] = bih[2 * HID + j];
    bnh[j] = bhh[2 * HID + j];
}

// ---------------- pack all weights into B-fragment order ----------------
#define NG (5 * 32 * 64 * 8)
#define N1 (4 * 9 * 64 * 8)
#define N2 (4 * 3 * 64 * 8)
__global__ void pack_all_kernel(const float* __restrict__ Wih, const float* __restrict__ Whh,
                                const float* __restrict__ fc1, const float* __restrict__ va1,
                                const float* __restrict__ vd1, const float* __restrict__ fc2,
                                const float* __restrict__ va2, const float* __restrict__ vd2,
                                unsigned short* __restrict__ Wg, unsigned short* __restrict__ F1p,
                                unsigned short* __restrict__ F2p)
{
    int idx = blockIdx.x * 256 + threadIdx.x;
    if (idx < NG) {
        int j = idx & 7, lane = (idx >> 3) & 63, tile = idx >> 9;
        int ct = tile & 31, kc = tile >> 5;
        int c = ct * 16 + (lane & 15);
        int k = kc * 32 + (lane >> 4) * 8 + j;
        float v;
        if (c < 256)      v = (k < 32) ? Wih[(size_t)c * 32 + k] : Whh[(size_t)c * 128 + (k - 32)];
        else if (c < 384) v = (k < 32) ? Wih[(size_t)c * 32 + k] : 0.0f;
        else              v = (k < 32) ? 0.0f : Whh[(size_t)(c - 128) * 128 + (k - 32)];
        Wg[idx] = f2bf(v);
    } else if (idx < NG + N1) {
        int i1 = idx - NG;
        int j = i1 & 7, lane = (i1 >> 3) & 63, tile = i1 >> 9;
        int ct = tile % 9, kc = tile / 9;
        int c = ct * 16 + (lane & 15);
        int k = kc * 32 + (lane >> 4) * 8 + j;
        float v;
        if (c < 128)       v = fc1[(size_t)c * 128 + k];
        else if (c == 128) v = va1[k];
        else if (c == 129) v = vd1[k];
        else               v = 0.0f;
        F1p[i1] = f2bf(v);
    } else if (idx < NG + N1 + N2) {
        int i2 = idx - NG - N1;
        int j = i2 & 7, lane = (i2 >> 3) & 63, tile = i2 >> 9;
        int ct = tile % 3, kc = tile / 3;
        int c = ct * 16 + (lane & 15);
        int k = kc * 32 + (lane >> 4) * 8 + j;
        float v;
        if (c < 32)       v = fc2[(size_t)c * 128 + k];
        else if (c == 32) v = va2[k];
        else if (c == 33) v = vd2[k];
        else              v = 0.0f;
        F2p[i2] = f2bf(v);
    }
}

// ---------------- KA: [gat2(t-1) + state update + out] + GRU + z1ext (256 thr, BM=16) ----------------
__global__ __launch_bounds__(256)
void kA(const unsigned short* __restrict__ xbf, const unsigned short* __restrict__ hin,
        unsigned short* __restrict__ hout,
        const unsigned short* __restrict__ Wg, const unsigned short* __restrict__ Fc1,
        const float* __restrict__ br, const float* __restrict__ bz,
        const float* __restrict__ bni, const float* __restrict__ bnh,
        unsigned short* __restrict__ z1, float* __restrict__ ps1, float* __restrict__ pd1,
        const unsigned short* __restrict__ z2, const float* __restrict__ ps2,
        const float* __restrict__ pd2, const int* __restrict__ src,
        float* __restrict__ state, float* __restrict__ out, const float* __restrict__ tarr,
        int tstep, int N, int T)
{
    __shared__ unsigned short A[BM][APAD];   // [x | h_old], later z1 staging
    __shared__ unsigned short Ht[BM][HPAD];  // h_new
    __shared__ int   sE[BM][DEG];
    __shared__ float aE[BM][DEG];

    const int tid = threadIdx.x, lane = tid & 63, w = tid >> 6;  // 4 waves
    const int n0 = blockIdx.x * BM;
    const int row = lane & 15, kg = lane >> 4;
    const int rn = tid >> 4, le = tid & 15;   // node-local (0..15) / edge-or-colslice (0..15)

    // stage h_old: one bf16x8 per thread (16 rows x 16 segs)
    {
        int n = n0 + rn;
        bf16x8 v = {0, 0, 0, 0, 0, 0, 0, 0};
        if (n < N) v = *(const bf16x8*)(hin + (size_t)n * HID + le * 8);
        *(bf16x8*)&A[rn][32 + le * 8] = v;
    }

    if (tstep == 0) {
        if (tid < BM * 4) {
            int r = tid >> 2, seg = tid & 3, n = n0 + r;
            bf16x8 v = {0, 0, 0, 0, 0, 0, 0, 0};
            if (n < N) v = *(const bf16x8*)(xbf + (size_t)n * IN_DIM + seg * 8);
            *(bf16x8*)&A[r][seg * 8] = v;
        }
    } else {
        // ---- fused gat2 of step t-1 ----
        // scores: 1 edge per thread (256 = 16 nodes x 16 edges)
        {
            int i = n0 + rn;
            int s = 0; float e = -3.0e38f;
            if (i < N) {
                s = src[i * DEG + le];
                e = lreluf(ps2[s] + pd2[i]);
            }
            float m = e;
            m = fmaxf(m, __shfl_xor(m, 8));
            m = fmaxf(m, __shfl_xor(m, 4));
            m = fmaxf(m, __shfl_xor(m, 2));
            m = fmaxf(m, __shfl_xor(m, 1));
            float ee = __expf(e - m);
            float sum = ee;
            sum += __shfl_xor(sum, 8);
            sum += __shfl_xor(sum, 4);
            sum += __shfl_xor(sum, 2);
            sum += __shfl_xor(sum, 1);
            sE[rn][le] = s;
            aE[rn][le] = ee / sum;
        }
        __syncthreads();
        // aggregate: thread = (node rn, cols c2..c2+1)
        {
            const int c2 = le * 2;
            float a0 = 0.0f, a1 = 0.0f;
            #pragma unroll
            for (int k = 0; k < DEG; ++k) {
                int   s = sE[rn][k];       // LDS broadcast
                float a = aE[rn][k];
                unsigned int v = *(const unsigned int*)(z2 + (size_t)s * IN_DIM + c2);
                a0 = fmaf(a, bflo(v), a0);
                a1 = fmaf(a, bfhi(v), a1);
            }
            int i = n0 + rn;
            if (i < N) {
                float dt = tarr[tstep] - tarr[tstep - 1];
                float sv0 = state[(size_t)i * IN_DIM + c2];
                float sv1 = state[(size_t)i * IN_DIM + c2 + 1];
                float sn0 = fmaf(dt, a0, sv0);
                float sn1 = fmaf(dt, a1, sv1);
                state[(size_t)i * IN_DIM + c2]     = sn0;
                state[(size_t)i * IN_DIM + c2 + 1] = sn1;
                size_t ob = ((size_t)(tstep - 1) * N + i) * (2 * IN_DIM);
                out[ob + IN_DIM + c2]     = a0;
                out[ob + IN_DIM + c2 + 1] = a1;
                out[ob + (size_t)N * (2 * IN_DIM) + c2]     = sn0;
                out[ob + (size_t)N * (2 * IN_DIM) + c2 + 1] = sn1;
                A[rn][c2]     = f2bf(sn0);
                A[rn][c2 + 1] = f2bf(sn1);
            }
        }
    }
    __syncthreads();

    // ---- GEMM1: gates[16 x 512]; wave w does ctq = w*2 + q (q=0..1) ----
    #pragma unroll 1
    for (int q = 0; q < 2; ++q) {
        int ctq = w * 2 + q;
        f32x4 acc0 = {0,0,0,0}, acc1 = {0,0,0,0}, acc2 = {0,0,0,0}, acc3 = {0,0,0,0};
        #pragma unroll
        for (int kc = 0; kc < 5; ++kc) {
            bf16x8 a = *(const bf16x8*)&A[row][kc * 32 + kg * 8];
            const unsigned short* bp = Wg + ((size_t)(kc * 32 + ctq) * 64 + lane) * 8;
            bf16x8 b0 = *(const bf16x8*)(bp);
            bf16x8 b1 = *(const bf16x8*)(bp + (size_t)8  * 64 * 8);
            bf16x8 b2 = *(const bf16x8*)(bp + (size_t)16 * 64 * 8);
            bf16x8 b3 = *(const bf16x8*)(bp + (size_t)24 * 64 * 8);
            acc0 = mfma16(a, b0, acc0);
            acc1 = mfma16(a, b1, acc1);
            acc2 = mfma16(a, b2, acc2);
            acc3 = mfma16(a, b3, acc3);
        }
        int col = ctq * 16 + row;
        float brv = br[col], bzv = bz[col], bniv = bni[col], bnhv = bnh[col];
        #pragma unroll
        for (int rr = 0; rr < 4; ++rr) {
            int r_loc = kg * 4 + rr;
            float rg = sigf(acc0[rr] + brv);
            float zg = sigf(acc1[rr] + bzv);
            float nc = tanhfast(acc2[rr] + bniv + rg * (acc3[rr] + bnhv));
            float hold = bf2f(A[r_loc][32 + col]);
            Ht[r_loc][col] = f2bf((1.0f - zg) * nc + zg * hold);
        }
    }
    __syncthreads();

    // h_new -> global: one bf16x8 per thread
    {
        int n = n0 + rn;
        if (n < N) *(bf16x8*)(hout + (size_t)n * HID + le * 8) = *(const bf16x8*)&Ht[rn][le * 8];
    }

    // ---- GEMM2: z1ext[16 x 144]; 9 ctiles over 4 waves ----
    #pragma unroll 1
    for (int ct = w; ct < 9; ct += 4) {
        f32x4 acc = {0, 0, 0, 0};
        #pragma unroll
        for (int kc = 0; kc < 4; ++kc) {
            bf16x8 a = *(const bf16x8*)&Ht[row][kc * 32 + kg * 8];
            bf16x8 b = *(const bf16x8*)(Fc1 + ((size_t)(kc * 9 + ct) * 64 + lane) * 8);
            acc = mfma16(a, b, acc);
        }
        int col = ct * 16 + row;
        #pragma unroll
        for (int rr = 0; rr < 4; ++rr) {
            int r_loc = kg * 4 + rr;
            int n = n0 + r_loc;
            if (col < 128)                A[r_loc][col] = f2bf(acc[rr]);
            else if (n < N && col == 128) ps1[n] = acc[rr];
            else if (n < N && col == 129) pd1[n] = acc[rr];
        }
    }
    __syncthreads();

    // z1 -> global: one bf16x8 per thread
    {
        int n = n0 + rn;
        if (n < N) *(bf16x8*)(z1 + (size_t)n * HID + le * 8) = *(const bf16x8*)&A[rn][le * 8];
    }
}

// ---------------- KB: gat1 aggregate + z2ext GEMM (256 thr, BM=16) ----------------
__global__ __launch_bounds__(256)
void kB(const unsigned short* __restrict__ z1, const float* __restrict__ ps1,
        const float* __restrict__ pd1, const int* __restrict__ src,
        const unsigned short* __restrict__ Fc2,
        unsigned short* __restrict__ z2, float* __restrict__ ps2,
        float* __restrict__ pd2, int N)
{
    __shared__ unsigned short G[BM][HPAD];
    __shared__ unsigned short Z[BM][ZPAD];
    __shared__ int   sE[BM][DEG];
    __shared__ float aE[BM][DEG];

    const int tid = threadIdx.x, lane = tid & 63, w = tid >> 6;
    const int n0 = blockIdx.x * BM;
    const int row = lane & 15, kg = lane >> 4;
    const int rn = tid >> 4, le = tid & 15;

    // scores: 1 edge per thread
    {
        int i = n0 + rn;
        int s = 0; float e = -3.0e38f;
        if (i < N) {
            s = src[i * DEG + le];
            e = lreluf(ps1[s] + pd1[i]);
        }
        float m = e;
        m = fmaxf(m, __shfl_xor(m, 8));
        m = fmaxf(m, __shfl_xor(m, 4));
        m = fmaxf(m, __shfl_xor(m, 2));
        m = fmaxf(m, __shfl_xor(m, 1));
        float ee = __expf(e - m);
        float sum = ee;
        sum += __shfl_xor(sum, 8);
        sum += __shfl_xor(sum, 4);
        sum += __shfl_xor(sum, 2);
        sum += __shfl_xor(sum, 1);
        sE[rn][le] = s;
        aE[rn][le] = ee / sum;
    }
    __syncthreads();

    // aggregate: thread = (node rn, cols le*8 .. le*8+7); per edge 16B coalesced
    {
        const int c8 = le * 8;
        float ac[8] = {0, 0, 0, 0, 0, 0, 0, 0};
        #pragma unroll
        for (int k = 0; k < DEG; ++k) {
            int   s = sE[rn][k];
            float a = aE[rn][k];
            const unsigned int* zp = (const unsigned int*)(z1 + (size_t)s * HID + c8);
            unsigned int v0 = zp[0], v1 = zp[1], v2 = zp[2], v3 = zp[3];
            ac[0] = fmaf(a, bflo(v0), ac[0]);
            ac[1] = fmaf(a, bfhi(v0), ac[1]);
            ac[2] = fmaf(a, bflo(v1), ac[2]);
            ac[3] = fmaf(a, bfhi(v1), ac[3]);
            ac[4] = fmaf(a, bflo(v2), ac[4]);
            ac[5] = fmaf(a, bfhi(v2), ac[5]);
            ac[6] = fmaf(a, bflo(v3), ac[6]);
            ac[7] = fmaf(a, bfhi(v3), ac[7]);
        }
        #pragma unroll
        for (int j = 0; j < 8; ++j) G[rn][c8 + j] = f2bf(fmaxf(ac[j], 0.0f));
    }
    __syncthreads();

    // z2ext[16 x 48]: 3 ctiles over 4 waves (w = 0..2 active)
    if (w < 3) {
        int ct = w;
        f32x4 acc = {0, 0, 0, 0};
        #pragma unroll
        for (int kc = 0; kc < 4; ++kc) {
            bf16x8 a = *(const bf16x8*)&G[row][kc * 32 + kg * 8];
            bf16x8 b = *(const bf16x8*)(Fc2 + ((size_t)(kc * 3 + ct) * 64 + lane) * 8);
            acc = mfma16(a, b, acc);
        }
        int col = ct * 16 + row;
        #pragma unroll
        for (int rr = 0; rr < 4; ++rr) {
            int r_loc = kg * 4 + rr;
            int n = n0 + r_loc;
            if (col < 32)                Z[r_loc][col] = f2bf(acc[rr]);
            else if (n < N && col == 32) ps2[n] = acc[rr];
            else if (n < N && col == 33) pd2[n] = acc[rr];
        }
    }
    __syncthreads();

    if (tid < BM * 4) {
        int r = tid >> 2, seg = tid & 3, n = n0 + r;
        if (n < N) *(bf16x8*)(z2 + (size_t)n * IN_DIM + seg * 8) = *(const bf16x8*)&Z[r][seg * 8];
    }
}

// ---------------- tail: gat2 for t = T-1 (xii only) ----------------
__global__ __launch_bounds__(256)
void kTail(const unsigned short* __restrict__ z2, const float* __restrict__ ps2,
           const float* __restrict__ pd2, const int* __restrict__ src,
           float* __restrict__ out, int N, int T)
{
    __shared__ int   sE[BM][DEG];
    __shared__ float aE[BM][DEG];
    const int tid = threadIdx.x;
    const int n0 = blockIdx.x * BM;
    const int rn = tid >> 4, le = tid & 15;

    {
        int i = n0 + rn;
        int s = 0; float e = -3.0e38f;
        if (i < N) {
            s = src[i * DEG + le];
            e = lreluf(ps2[s] + pd2[i]);
        }
        float m = e;
        m = fmaxf(m, __shfl_xor(m, 8));
        m = fmaxf(m, __shfl_xor(m, 4));
        m = fmaxf(m, __shfl_xor(m, 2));
        m = fmaxf(m, __shfl_xor(m, 1));
        float ee = __expf(e - m);
        float sum = ee;
        sum += __shfl_xor(sum, 8);
        sum += __shfl_xor(sum, 4);
        sum += __shfl_xor(sum, 2);
        sum += __shfl_xor(sum, 1);
        sE[rn][le] = s;
        aE[rn][le] = ee / sum;
    }
    __syncthreads();

    {
        const int c2 = le * 2;
        float a0 = 0.0f, a1 = 0.0f;
        #pragma unroll
        for (int k = 0; k < DEG; ++k) {
            int   s = sE[rn][k];
            float a = aE[rn][k];
            unsigned int v = *(const unsigned int*)(z2 + (size_t)s * IN_DIM + c2);
            a0 = fmaf(a, bflo(v), a0);
            a1 = fmaf(a, bfhi(v), a1);
        }
        int i = n0 + rn;
        if (i < N) {
            size_t ob = ((size_t)(T - 1) * N + i) * (2 * IN_DIM);
            out[ob + IN_DIM + c2]     = a0;
            out[ob + IN_DIM + c2 + 1] = a1;
        }
    }
}

extern "C" void kernel_launch(void* const* d_in, const int* in_sizes, int n_in,
                              void* d_out, int out_size, void* d_ws, size_t ws_size,
                              hipStream_t stream)
{
    const float* tarr  = (const float*)d_in[0];
    const float* x0    = (const float*)d_in[1];
    const int*   src   = (const int*)d_in[2];
    // d_in[3] = dst (structural: repeat(arange(N), DEG))
    const float* Wih   = (const float*)d_in[4];
    const float* Whh   = (const float*)d_in[5];
    const float* bih   = (const float*)d_in[6];
    const float* bhh   = (const float*)d_in[7];
    const float* fc1   = (const float*)d_in[8];
    const float* attn1 = (const float*)d_in[9];
    const float* fc2   = (const float*)d_in[10];
    const float* attn2 = (const float*)d_in[11];
    float* out = (float*)d_out;

    const int T = in_sizes[0];
    const int N = in_sizes[1] / IN_DIM;

    // f32 region
    float* fp = (float*)d_ws;
    float* state = fp; fp += (size_t)N * IN_DIM;
    float* ps1 = fp; fp += N;
    float* pd1 = fp; fp += N;
    float* ps2 = fp; fp += N;
    float* pd2 = fp; fp += N;
    float* va1 = fp; fp += HID;
    float* vd1 = fp; fp += HID;
    float* va2 = fp; fp += HID;
    float* vd2 = fp; fp += HID;
    float* br  = fp; fp += HID;
    float* bz  = fp; fp += HID;
    float* bni = fp; fp += HID;
    float* bnh = fp; fp += HID;
    // bf16 region
    unsigned short* up = (unsigned short*)fp;
    unsigned short* state_bf = up; up += (size_t)N * IN_DIM;
    unsigned short* hA  = up; up += (size_t)N * HID;
    unsigned short* hB  = up; up += (size_t)N * HID;
    unsigned short* z1  = up; up += (size_t)N * HID;
    unsigned short* z2  = up; up += (size_t)N * IN_DIM;
    unsigned short* Wg  = up; up += NG;
    unsigned short* F1p = up; up += N1;
    unsigned short* F2p = up; up += N2;

    const int nblk = (N + BM - 1) / BM;

    init_kernel<<<(N * HID + 255) / 256, 256, 0, stream>>>(x0, state, state_bf, hA, out, N);
    prep_kernel<<<1, 128, 0, stream>>>(fc1, attn1, fc2, attn2, bih, bhh,
                                       va1, vd1, va2, vd2, br, bz, bni, bnh);
    pack_all_kernel<<<(NG + N1 + N2 + 255) / 256, 256, 0, stream>>>(
        Wih, Whh, fc1, va1, vd1, fc2, va2, vd2, Wg, F1p, F2p);

    for (int t = 0; t < T; ++t) {
        const unsigned short* hin   = (t & 1) ? hB : hA;
        unsigned short*       houtp = (t & 1) ? hA : hB;

        kA<<<nblk, 256, 0, stream>>>(state_bf, hin, houtp, Wg, F1p,
                                     br, bz, bni, bnh, z1, ps1, pd1,
                                     z2, ps2, pd2, src, state, out, tarr, t, N, T);
        kB<<<nblk, 256, 0, stream>>>(z1, ps1, pd1, src, F2p, z2, ps2, pd2, N);
    }
    kTail<<<nblk, 256, 0, stream>>>(z2, ps2, pd2, src, out, N, T);
}